// Round 15
// baseline (476.298 us; speedup 1.0000x reference)
//
#include <hip/hip_runtime.h>
#include <hip/hip_cooperative_groups.h>
#include <math.h>
#include <stdint.h>

namespace cg = cooperative_groups;

#define NB 8
#define P_TOTAL 13343
#define NCLS 80
#define KTOP 1000
#define PPAD 16384
#define BCAP 256
#define D_SCORE_THR 0.05
#define D_IOU_THR 0.6

// ---------------- helpers ----------------

__device__ __forceinline__ double sig64(double x) {
    if (x >= 0.0) {
        double e = exp(-x);
        return 1.0 / (1.0 + e);
    } else {
        double e = exp(x);
        return e / (1.0 + e);
    }
}

__device__ __forceinline__ uint64_t pack_key(double s, int p) {
    uint64_t b = (uint64_t)__double_as_longlong(s);
    return (b & ~0x3FFFull) | (uint64_t)(0x3FFF - p);
}

__device__ __forceinline__ double key_score(uint64_t key) {
    return __longlong_as_double((long long)(key & ~0x3FFFull));
}

__device__ __forceinline__ int val_bin(double s) {
    int bin = (int)(s * 2048.0);
    return bin < 0 ? 0 : (bin > 2047 ? 2047 : bin);
}

__device__ __forceinline__ uint64_t rl64(uint64_t v, int l) {
    uint32_t lo = (uint32_t)__builtin_amdgcn_readlane((int)(uint32_t)v, l);
    uint32_t hi = (uint32_t)__builtin_amdgcn_readlane((int)(uint32_t)(v >> 32), l);
    return ((uint64_t)hi << 32) | lo;
}

__device__ __forceinline__ unsigned long long enc64(double x) {
    long long u = __double_as_longlong(x);
    return (unsigned long long)(u < 0 ? ~u : (u | 0x8000000000000000ll));
}
__device__ __forceinline__ double dec64(unsigned long long e) {
    long long u = (e >> 63) ? (long long)(e & 0x7FFFFFFFFFFFFFFFull) : ~(long long)e;
    return __longlong_as_double(u);
}

struct Params {
    const float *c0, *c1, *c2, *c3, *c4;
    const float *n0, *n1, *n2, *n3, *n4;
    const float *r0, *r1, *r2, *r3, *r4;
    uint64_t* packed;
    int* classes;
    uint32_t* bcnt;          // per-bin count (histogram) -- zeroed in P0
    uint64_t* bucket;        // per-bin keys, cap BCAP
    double4* rawbox;
    float* clsall;
    float *outs, *outc, *outb;
    uint64_t* keepw;
    unsigned long long* pmaxE;
    uint64_t *M, *D;
    uint32_t* Rnz;
    float* out;
};

union Sm {
    struct {
        uint32_t lh[2048];
        uint32_t chs[64];
        uint32_t chsuf[64];
        uint64_t pass[512];
        double redw[4];
        int sB, sNP;
    } rp;
    struct {
        double lx1[1024], ly1[1024], lx2[1024], ly2[1024], lar[1024];
        float4 fbox[1024];
        uint64_t ornz[4][64];
    } mk;
};

// ---------------- the single fused cooperative kernel ----------------

__global__ __launch_bounds__(256) void k_fused(Params gp)
{
    __shared__ Sm sm;
    cg::grid_group grid = cg::this_grid();
    int tid = threadIdx.x;
    int bx = blockIdx.x;
    int lane = tid & 63, wid = tid >> 6;

    // ---- P0: zero scratch (replaces memset dispatch) ----
    {
        int zid = bx * 256 + tid;
        if (zid < NB * 2048) gp.bcnt[zid] = 0;
        else if (zid < NB * 2048 + 128) gp.keepw[zid - NB * 2048] = 0ull;
        else if (zid < NB * 2048 + 136) gp.pmaxE[zid - NB * 2048 - 128] = 0ull;
    }
    __threadfence();
    grid.sync();

    // ---- P1: scores/classes -> keys + bin counts + buckets ----
    {
        int gid = bx * 256 + tid;            // 512*256 == NB*PPAD exactly
        int b = gid >> 14;
        int pp = gid & (PPAD - 1);
        if (pp >= P_TOTAL) {
            gp.packed[gid] = 0;
        } else {
            int base, hw;
            const float* cls;
            const float* cnt;
            if (pp < 10000)      { base = 0;     hw = 10000; cls = gp.c0; cnt = gp.n0; }
            else if (pp < 12500) { base = 10000; hw = 2500;  cls = gp.c1; cnt = gp.n1; }
            else if (pp < 13125) { base = 12500; hw = 625;   cls = gp.c2; cnt = gp.n2; }
            else if (pp < 13294) { base = 13125; hw = 169;   cls = gp.c3; cnt = gp.n3; }
            else                 { base = 13294; hw = 49;    cls = gp.c4; cnt = gp.n4; }
            int yx = pp - base;

            // argmax over 80 logits; two 40-chains for ILP; first-max ties kept.
            const float* cp = cls + (size_t)b * NCLS * hw + yx;
            float m0 = -3.4e38f, m1 = -3.4e38f;
            int a0 = 0, a1 = 40;
            for (int c = 0; c < 40; ++c) {
                float v0 = cp[(size_t)c * hw];
                float v1 = cp[(size_t)(c + 40) * hw];
                if (v0 > m0) { m0 = v0; a0 = c; }
                if (v1 > m1) { m1 = v1; a1 = c + 40; }
            }
            float m = m0; int am = a0;
            if (m1 > m0) { m = m1; am = a1; }

            float cv = cnt[(size_t)b * hw + yx];
            double s = sqrt(sig64((double)m) * sig64((double)cv));

            uint64_t key = pack_key(s, pp);
            gp.packed[gid] = key;
            gp.classes[(size_t)b * P_TOTAL + pp] = am + 1;

            int bn = val_bin(key_score(key));       // bin from MASKED key score
            uint32_t slot = atomicAdd(&gp.bcnt[b * 2048 + bn], 1u);
            if (slot < BCAP)
                gp.bucket[((size_t)b * 2048 + bn) * BCAP + slot] = key;
        }
    }
    __threadfence();
    grid.sync();

    // ---- P2: analytic-rank select + gather (blocks 0..255) ----
    if (bx < 256) {
        int b = bx >> 5, g = bx & 31;
        const uint64_t* pk = gp.packed + (size_t)b * PPAD;

        for (int t = tid; t < 2048; t += 256) sm.rp.lh[t] = gp.bcnt[b * 2048 + t];
        if (tid == 0) sm.rp.sNP = 0;
        __syncthreads();

        if (tid < 64) {
            uint32_t ss = 0;
            for (int i = 0; i < 32; ++i) ss += sm.rp.lh[tid * 32 + i];
            sm.rp.chs[tid] = ss;
        }
        __syncthreads();
        if (wid == 0) {
            uint32_t v = sm.rp.chs[63 - lane];
            uint32_t P = v;
            for (int d = 1; d < 64; d <<= 1) {
                uint32_t u = __shfl_up(P, d, 64);
                if (lane >= d) P += u;
            }
            sm.rp.chsuf[63 - lane] = P - v;
            uint64_t bal = __ballot(P >= 1024u);
            int lstar = __builtin_ctzll(bal);
            int cstar = 63 - lstar;
            uint32_t Pst = (uint32_t)__shfl((int)P, lstar, 64);
            uint32_t C1c = Pst - sm.rp.chs[cstar];
            uint32_t w = (lane < 32) ? sm.rp.lh[cstar * 32 + 31 - lane] : 0u;
            uint32_t Q = w;
            for (int d = 1; d < 32; d <<= 1) {
                uint32_t u = __shfl_up(Q, d, 64);
                if (lane >= d) Q += u;
            }
            uint64_t bal2 = __ballot((lane < 32) && (C1c + Q >= 1024u));
            int l2 = __builtin_ctzll(bal2);
            if (lane == 0) sm.rp.sB = cstar * 32 + 31 - l2;
        }
        __syncthreads();
        int B = sm.rp.sB;

        // slice passers
        int src0 = g * 512;
#pragma unroll
        for (int k = 0; k < 2; ++k) {
            uint64_t key = pk[src0 + tid + k * 256];
            bool pred = (key != 0ull) && (val_bin(key_score(key)) >= B);
            uint64_t bal = __ballot(pred);
            int bs = 0;
            if (lane == 0 && bal) bs = atomicAdd(&sm.rp.sNP, (int)__popcll(bal));
            bs = __shfl(bs, 0, 64);
            if (pred) sm.rp.pass[bs + __popcll(bal & ((1ull << lane) - 1ull))] = key;
        }
        __syncthreads();
        int np = sm.rp.sNP;

        double lm = -1e300;
        if (tid < np) {
            uint64_t key = sm.rp.pass[tid];
            double s = key_score(key);
            int bin = val_bin(s);
            int c = bin >> 5;
            uint32_t rank = sm.rp.chsuf[c];
            for (int j = bin + 1; j < (c + 1) * 32; ++j) rank += sm.rp.lh[j];
            uint32_t bc = gp.bcnt[b * 2048 + bin];
            if (bc <= BCAP) {
                const uint64_t* bk = gp.bucket + ((size_t)b * 2048 + bin) * BCAP;
                for (uint32_t i = 0; i < bc; ++i) rank += (bk[i] > key) ? 1u : 0u;
            } else {
                for (int t2 = 0; t2 < PPAD; ++t2) {   // exact fallback (never taken)
                    uint64_t k2 = pk[t2];
                    if (k2 > key && val_bin(key_score(k2)) == bin) ++rank;
                }
            }

            if (rank < 1024u) {
                int idx = 0x3FFF - (int)(key & 0x3FFF);
                idx = idx < 0 ? 0 : (idx > P_TOTAL - 1 ? P_TOTAL - 1 : idx);

                int base2, w2, hw, st;
                const float* reg;
                if (idx < 10000)      { base2 = 0;     w2 = 100; hw = 10000; st = 8;   reg = gp.r0; }
                else if (idx < 12500) { base2 = 10000; w2 = 50;  hw = 2500;  st = 16;  reg = gp.r1; }
                else if (idx < 13125) { base2 = 12500; w2 = 25;  hw = 625;   st = 32;  reg = gp.r2; }
                else if (idx < 13294) { base2 = 13125; w2 = 13;  hw = 169;   st = 64;  reg = gp.r3; }
                else                  { base2 = 13294; w2 = 7;   hw = 49;    st = 128; reg = gp.r4; }
                int yx = idx - base2;
                int y = yx / w2;
                int x = yx - y * w2;
                double sx = (double)(x * st + st / 2);
                double sy = (double)(y * st + st / 2);
                const float* rp2 = reg + (size_t)b * 4 * hw + yx;
                double x1 = sx - (double)rp2[0];
                double y1 = sy - (double)rp2[hw];
                double x2 = sx + (double)rp2[2 * (size_t)hw];
                double y2 = sy + (double)rp2[3 * (size_t)hw];
                int cv = gp.classes[(size_t)b * P_TOTAL + idx];

                bool valid = (rank < KTOP) && (s >= D_SCORE_THR);
                size_t ix = (size_t)b * 1024 + rank;
                gp.rawbox[ix] = make_double4(x1, y1, x2, y2);
                gp.clsall[ix] = (float)cv;
                if (rank < KTOP) {
                    gp.outs[ix] = (float)s;
                    gp.outc[ix] = (float)cv;
                    ((float4*)gp.outb)[ix] = make_float4((float)x1, (float)y1,
                                                         (float)x2, (float)y2);
                    lm = valid ? fmax(fmax(x1, y1), fmax(x2, y2)) : 0.0;
                }
                if (valid)
                    atomicOr((unsigned long long*)&gp.keepw[(size_t)b * 16 + (rank >> 6)],
                             1ull << (rank & 63));
            }
        }

        for (int d = 1; d < 64; d <<= 1)
            lm = fmax(lm, __shfl_xor(lm, d, 64));
        if (lane == 0) sm.rp.redw[wid] = lm;
        __syncthreads();
        if (tid == 0) {
            double mm = fmax(fmax(sm.rp.redw[0], sm.rp.redw[1]),
                             fmax(sm.rp.redw[2], sm.rp.redw[3]));
            atomicMax(&gp.pmaxE[b], enc64(mm));
        }
    }
    __threadfence();
    grid.sync();

    // ---- P3: mask matrix (blocks 0..127) ----
    if (bx < 128) {
        int b = bx >> 4, rb = bx & 15;

        double offscale = dec64(gp.pmaxE[b]) + 1.0;

        for (int t = tid; t < 1024; t += 256) {
            size_t ix = (size_t)b * 1024 + t;
            double4 rb4 = gp.rawbox[ix];
            double o = (double)gp.clsall[ix] * offscale;
            double ox1 = rb4.x + o, oy1 = rb4.y + o;
            double ox2 = rb4.z + o, oy2 = rb4.w + o;
            sm.mk.lx1[t] = ox1; sm.mk.ly1[t] = oy1;
            sm.mk.lx2[t] = ox2; sm.mk.ly2[t] = oy2;
            sm.mk.lar[t] = (ox2 - ox1 + 1.0) * (oy2 - oy1 + 1.0);
            sm.mk.fbox[t] = make_float4((float)ox1, (float)oy1, (float)ox2, (float)oy2);
        }
        __syncthreads();

        int ww = wid;
        int l  = lane;
        int r  = rb * 64 + l;
        float4 fr = sm.mk.fbox[r];
        double rx1 = sm.mk.lx1[r], ry1 = sm.mk.ly1[r];
        double rx2 = sm.mk.lx2[r], ry2 = sm.mk.ly2[r], ra = sm.mk.lar[r];
        int wbase = ww * 4;

        uint64_t bits0 = 0, bits1 = 0, bits2 = 0, bits3 = 0;

#define COLWORD(Q, BITS)                                                       \
        {                                                                      \
            int cb = (wbase + (Q)) * 64;                                       \
            if (cb + 63 > r) {                                                 \
                for (int kk = 0; kk < 64; ++kk) {                              \
                    int j = cb + kk;                                           \
                    float4 fb = sm.mk.fbox[j];                                 \
                    float xm = fminf(fb.z, fr.z) - fmaxf(fb.x, fr.x);          \
                    float ym = fminf(fb.w, fr.w) - fmaxf(fb.y, fr.y);          \
                    if (xm > -0.5f && ym > -0.5f) {                            \
                        double xmn = fmax(sm.mk.lx1[j], rx1);                  \
                        double ymn = fmax(sm.mk.ly1[j], ry1);                  \
                        double xmx = fmin(sm.mk.lx2[j], rx2);                  \
                        double ymx = fmin(sm.mk.ly2[j], ry2);                  \
                        double iw = xmx - xmn; iw = iw < 0.0 ? 0.0 : iw;       \
                        double ih = ymx - ymn; ih = ih < 0.0 ? 0.0 : ih;       \
                        double inter = iw * ih;                                \
                        double iou = inter / (ra + sm.mk.lar[j] - inter);      \
                        BITS |= ((uint64_t)((j > r) && (iou > D_IOU_THR))) << kk; \
                    }                                                          \
                }                                                              \
            }                                                                  \
        }

        COLWORD(0, bits0) COLWORD(1, bits1) COLWORD(2, bits2) COLWORD(3, bits3)
#undef COLWORD

        size_t mrow = ((size_t)b * 1024 + r) * 16 + wbase;
        gp.M[mrow + 0] = bits0; gp.M[mrow + 1] = bits1;
        gp.M[mrow + 2] = bits2; gp.M[mrow + 3] = bits3;

        if (ww == (rb >> 2)) {
            uint64_t db = (rb & 3) == 0 ? bits0 : (rb & 3) == 1 ? bits1
                        : (rb & 3) == 2 ? bits2 : bits3;
            gp.D[((size_t)b * 16 + rb) * 64 + l] = db;
        }

        sm.mk.ornz[ww][l] = bits0 | bits1 | bits2 | bits3;
        __syncthreads();
        if (ww == 0) {
            uint64_t o = sm.mk.ornz[0][l] | sm.mk.ornz[1][l]
                       | sm.mk.ornz[2][l] | sm.mk.ornz[3][l];
            gp.Rnz[(size_t)b * 1024 + r] = (o != 0) ? 1u : 0u;
        }
    }
    __threadfence();
    grid.sync();

    // ---- P4: one-wave sparse scan + output (blocks 0..7, lanes 0..63) ----
    if (bx < 8 && tid < 64) {
        int b = bx;
        int p = (lane >> 4) & 3;
        int w = lane & 15;
        const uint64_t* Mb = gp.M + (size_t)b * 1024 * 16;
        const uint64_t* Dp = gp.D + (size_t)b * 1024;
        const uint32_t* Rp = gp.Rnz + (size_t)b * 1024;

        uint64_t kw = gp.keepw[(size_t)b * 16 + w];

        uint32_t f0  = Rp[0 * 64 + lane],  f1  = Rp[1 * 64 + lane];
        uint32_t f2  = Rp[2 * 64 + lane],  f3  = Rp[3 * 64 + lane];
        uint32_t f4  = Rp[4 * 64 + lane],  f5  = Rp[5 * 64 + lane];
        uint32_t f6  = Rp[6 * 64 + lane],  f7  = Rp[7 * 64 + lane];
        uint32_t f8  = Rp[8 * 64 + lane],  f9  = Rp[9 * 64 + lane];
        uint32_t f10 = Rp[10 * 64 + lane], f11 = Rp[11 * 64 + lane];
        uint32_t f12 = Rp[12 * 64 + lane], f13 = Rp[13 * 64 + lane];
        uint32_t f14 = Rp[14 * 64 + lane], f15 = Rp[15 * 64 + lane];
        uint64_t nz0  = __ballot(f0 != 0),  nz1  = __ballot(f1 != 0);
        uint64_t nz2  = __ballot(f2 != 0),  nz3  = __ballot(f3 != 0);
        uint64_t nz4  = __ballot(f4 != 0),  nz5  = __ballot(f5 != 0);
        uint64_t nz6  = __ballot(f6 != 0),  nz7  = __ballot(f7 != 0);
        uint64_t nz8  = __ballot(f8 != 0),  nz9  = __ballot(f9 != 0);
        uint64_t nz10 = __ballot(f10 != 0), nz11 = __ballot(f11 != 0);
        uint64_t nz12 = __ballot(f12 != 0), nz13 = __ballot(f13 != 0);
        uint64_t nz14 = __ballot(f14 != 0), nz15 = __ballot(f15 != 0);

        uint64_t C0,C1,C2,C3,C4,C5,C6,C7,C8,C9,C10,C11,C12,C13,C14,C15;

#define LOADC(G)                                                               \
        C0  = Mb[((size_t)(G) * 64 +  0 + p) * 16 + w];                        \
        C1  = Mb[((size_t)(G) * 64 +  4 + p) * 16 + w];                        \
        C2  = Mb[((size_t)(G) * 64 +  8 + p) * 16 + w];                        \
        C3  = Mb[((size_t)(G) * 64 + 12 + p) * 16 + w];                        \
        C4  = Mb[((size_t)(G) * 64 + 16 + p) * 16 + w];                        \
        C5  = Mb[((size_t)(G) * 64 + 20 + p) * 16 + w];                        \
        C6  = Mb[((size_t)(G) * 64 + 24 + p) * 16 + w];                        \
        C7  = Mb[((size_t)(G) * 64 + 28 + p) * 16 + w];                        \
        C8  = Mb[((size_t)(G) * 64 + 32 + p) * 16 + w];                        \
        C9  = Mb[((size_t)(G) * 64 + 36 + p) * 16 + w];                        \
        C10 = Mb[((size_t)(G) * 64 + 40 + p) * 16 + w];                        \
        C11 = Mb[((size_t)(G) * 64 + 44 + p) * 16 + w];                        \
        C12 = Mb[((size_t)(G) * 64 + 48 + p) * 16 + w];                        \
        C13 = Mb[((size_t)(G) * 64 + 52 + p) * 16 + w];                        \
        C14 = Mb[((size_t)(G) * 64 + 56 + p) * 16 + w];                        \
        C15 = Mb[((size_t)(G) * 64 + 60 + p) * 16 + w];

#define APPLY_Q(q)                                                             \
        {                                                                      \
            uint64_t t_ = (alive >> (4 * (q) + p)) & 1ull;                     \
            acc &= ~(C##q & (0ull - t_));                                      \
        }

#define STEPG(G, NZ)                                                           \
        {                                                                      \
            uint64_t kg = rl64(kw, (G));                                       \
            if (kg & NZ) {                                                     \
                uint64_t dg = Dp[(size_t)(G) * 64 + lane];                     \
                LOADC(G)                                                       \
                uint64_t cur = kg, it = kg & NZ;                               \
                while (it) {                                                   \
                    int kk = __builtin_ctzll(it);                              \
                    uint64_t dk = rl64(dg, kk);                                \
                    cur &= ~dk;                                                \
                    it &= ~dk;                                                 \
                    it &= it - 1ull;                                           \
                }                                                              \
                uint64_t alive = cur;                                          \
                uint64_t acc = ~0ull;                                          \
                APPLY_Q(0)  APPLY_Q(1)  APPLY_Q(2)  APPLY_Q(3)                 \
                APPLY_Q(4)  APPLY_Q(5)  APPLY_Q(6)  APPLY_Q(7)                 \
                APPLY_Q(8)  APPLY_Q(9)  APPLY_Q(10) APPLY_Q(11)                \
                APPLY_Q(12) APPLY_Q(13) APPLY_Q(14) APPLY_Q(15)                \
                acc &= __shfl_xor(acc, 16, 64);                                \
                acc &= __shfl_xor(acc, 32, 64);                                \
                kw &= acc;                                                     \
            }                                                                  \
        }

        STEPG(0, nz0)   STEPG(1, nz1)   STEPG(2, nz2)   STEPG(3, nz3)
        STEPG(4, nz4)   STEPG(5, nz5)   STEPG(6, nz6)   STEPG(7, nz7)
        STEPG(8, nz8)   STEPG(9, nz9)   STEPG(10, nz10) STEPG(11, nz11)
        STEPG(12, nz12) STEPG(13, nz13) STEPG(14, nz14) STEPG(15, nz15)

#undef STEPG
#undef APPLY_Q
#undef LOADC

#pragma unroll
        for (int t = 0; t < 16; ++t) {
            int j = t * 64 + lane;
            uint64_t kwt = rl64(kw, t);
            bool kp = (kwt >> lane) & 1ull;
            if (j < KTOP) {
                size_t ix = (size_t)b * 1024 + j;
                gp.out[(size_t)b * KTOP + j] = kp ? gp.outs[ix] : 0.0f;
                gp.out[(size_t)NB * KTOP + (size_t)b * KTOP + j] = kp ? gp.outc[ix] : 0.0f;
                float4 bb = kp ? ((const float4*)gp.outb)[ix]
                               : make_float4(0.f, 0.f, 0.f, 0.f);
                ((float4*)(gp.out + 2 * (size_t)NB * KTOP))[(size_t)b * KTOP + j] = bb;
            }
        }
    }
}

// ---------------- launch ----------------

extern "C" void kernel_launch(void* const* d_in, const int* in_sizes, int n_in,
                              void* d_out, int out_size, void* d_ws, size_t ws_size,
                              hipStream_t stream) {
    char* ws = (char*)d_ws;

    Params prm;
    prm.c0 = (const float*)d_in[0];  prm.c1 = (const float*)d_in[1];
    prm.c2 = (const float*)d_in[2];  prm.c3 = (const float*)d_in[3];
    prm.c4 = (const float*)d_in[4];
    prm.n0 = (const float*)d_in[5];  prm.n1 = (const float*)d_in[6];
    prm.n2 = (const float*)d_in[7];  prm.n3 = (const float*)d_in[8];
    prm.n4 = (const float*)d_in[9];
    prm.r0 = (const float*)d_in[10]; prm.r1 = (const float*)d_in[11];
    prm.r2 = (const float*)d_in[12]; prm.r3 = (const float*)d_in[13];
    prm.r4 = (const float*)d_in[14];

    prm.packed  = (uint64_t*)(ws + 0);           // 1,048,576
    prm.M       = (uint64_t*)(ws + 0);           // reuse (packed dead before P3)
    prm.classes = (int*)(ws + 1048576);          // 426,976 -> 1,475,552
    prm.bcnt    = (uint32_t*)(ws + 1541088);     // 65,536  -> 1,606,624
    prm.bucket  = (uint64_t*)(ws + 1606624);     // 33,554,432 -> 35,161,056
    prm.rawbox  = (double4*)(ws + 35161056);     // 262,144 -> 35,423,200
    prm.clsall  = (float*)(ws + 35423200);       // 32,768 -> 35,455,968
    prm.pmaxE   = (unsigned long long*)(ws + 35455968);  // 64 -> 35,456,032
    prm.keepw   = (uint64_t*)(ws + 35456032);    // 1,024 -> 35,457,056
    prm.D       = (uint64_t*)(ws + 35457056);    // 65,536 -> 35,522,592
    prm.Rnz     = (uint32_t*)(ws + 35522592);    // 32,768 -> 35,555,360
    prm.outs    = (float*)(ws + 35555360);       // 32,768 -> 35,588,128
    prm.outc    = (float*)(ws + 35588128);       // 32,768 -> 35,620,896
    prm.outb    = (float*)(ws + 35620896);       // 131,072 -> 35,751,968
    prm.out     = (float*)d_out;

    void* kargs[] = { (void*)&prm };
    hipLaunchCooperativeKernel((const void*)k_fused, dim3(512), dim3(256),
                               kargs, 0, stream);
}

// Round 16
// 79.129 us; speedup vs baseline: 6.0193x; 6.0193x over previous
//
#include <hip/hip_runtime.h>
#include <math.h>
#include <stdint.h>

#define NB 8
#define P_TOTAL 13343
#define NCLS 80
#define KTOP 1000
#define PPAD 16384
#define BCAP 256
#define D_SCORE_THR 0.05
#define D_IOU_THR 0.6

// ---------------- helpers ----------------

__device__ __forceinline__ double sig64(double x) {
    if (x >= 0.0) {
        double e = exp(-x);
        return 1.0 / (1.0 + e);
    } else {
        double e = exp(x);
        return e / (1.0 + e);
    }
}

// key = score bits (top 50) | (0x3FFF - idx): descending order => score desc, idx asc
__device__ __forceinline__ uint64_t pack_key(double s, int p) {
    uint64_t b = (uint64_t)__double_as_longlong(s);
    return (b & ~0x3FFFull) | (uint64_t)(0x3FFF - p);
}

__device__ __forceinline__ double key_score(uint64_t key) {
    return __longlong_as_double((long long)(key & ~0x3FFFull));
}

__device__ __forceinline__ int val_bin(double s) {
    int bin = (int)(s * 2048.0);
    return bin < 0 ? 0 : (bin > 2047 ? 2047 : bin);
}

__device__ __forceinline__ uint64_t rl64(uint64_t v, int l) {
    uint32_t lo = (uint32_t)__builtin_amdgcn_readlane((int)(uint32_t)v, l);
    uint32_t hi = (uint32_t)__builtin_amdgcn_readlane((int)(uint32_t)(v >> 32), l);
    return ((uint64_t)hi << 32) | lo;
}

// order-preserving double -> u64 encoding (for atomicMax)
__device__ __forceinline__ unsigned long long enc64(double x) {
    long long u = __double_as_longlong(x);
    return (unsigned long long)(u < 0 ? ~u : (u | 0x8000000000000000ll));
}
__device__ __forceinline__ double dec64(unsigned long long e) {
    long long u = (e >> 63) ? (long long)(e & 0x7FFFFFFFFFFFFFFFull) : ~(long long)e;
    return __longlong_as_double(u);
}

// ---------------- S-1: zero scratch (replaces the 41us rocclr fill) -------------

__global__ __launch_bounds__(256) void k_zero(
    uint32_t* __restrict__ bcnt, uint64_t* __restrict__ keepw,
    unsigned long long* __restrict__ pmaxE)
{
    int gid = blockIdx.x * 256 + threadIdx.x;
    if (gid < NB * 2048) bcnt[gid] = 0;          // 16384 u32
    if (blockIdx.x == 0) {
        if (threadIdx.x < 128) keepw[threadIdx.x] = 0ull;
        else if (threadIdx.x < 136) pmaxE[threadIdx.x - 128] = 0ull;
    }
}

// ---------------- S0: scores/classes -> keys + bin counts + buckets -------------

__global__ __launch_bounds__(256) void k_scores(
    const float* __restrict__ c0, const float* __restrict__ c1, const float* __restrict__ c2,
    const float* __restrict__ c3, const float* __restrict__ c4,
    const float* __restrict__ n0, const float* __restrict__ n1, const float* __restrict__ n2,
    const float* __restrict__ n3, const float* __restrict__ n4,
    uint64_t* __restrict__ packed, int* __restrict__ classes,
    uint32_t* __restrict__ bcnt, uint64_t* __restrict__ bucket)
{
    int tid = threadIdx.x;
    int gid = blockIdx.x * 256 + tid;
    if (gid >= NB * PPAD) return;
    int b = gid >> 14;
    int p = gid & (PPAD - 1);
    if (p >= P_TOTAL) { packed[gid] = 0; return; }

    int base, hw;
    const float* cls;
    const float* cnt;
    if (p < 10000)      { base = 0;     hw = 10000; cls = c0; cnt = n0; }
    else if (p < 12500) { base = 10000; hw = 2500;  cls = c1; cnt = n1; }
    else if (p < 13125) { base = 12500; hw = 625;   cls = c2; cnt = n2; }
    else if (p < 13294) { base = 13125; hw = 169;   cls = c3; cnt = n3; }
    else                { base = 13294; hw = 49;    cls = c4; cnt = n4; }
    int yx = p - base;

    // argmax over 80 logits; two 40-chains for ILP; first-max ties preserved.
    const float* cp = cls + (size_t)b * NCLS * hw + yx;
    float m0 = -3.4e38f, m1 = -3.4e38f;
    int a0 = 0, a1 = 40;
    for (int c = 0; c < 40; ++c) {
        float v0 = cp[(size_t)c * hw];
        float v1 = cp[(size_t)(c + 40) * hw];
        if (v0 > m0) { m0 = v0; a0 = c; }
        if (v1 > m1) { m1 = v1; a1 = c + 40; }
    }
    float m = m0; int am = a0;
    if (m1 > m0) { m = m1; am = a1; }

    float cv = cnt[(size_t)b * hw + yx];
    double s = sqrt(sig64((double)m) * sig64((double)cv));

    uint64_t key = pack_key(s, p);
    packed[gid] = key;
    classes[(size_t)b * P_TOTAL + p] = am + 1;

    // single atomic: bucket slot counter doubles as the histogram (validated R15)
    int bn = val_bin(key_score(key));
    uint32_t slot = atomicAdd(&bcnt[b * 2048 + bn], 1u);
    if (slot < BCAP)
        bucket[((size_t)b * 2048 + bn) * BCAP + slot] = key;
}

// ---------------- S1: analytic-rank select+prep (no key-array rescans) ----------
// 256 blocks (32/batch). Block g owns source slice [g*512,(g+1)*512). rank(k) =
// suffix-hist(bin(k)) + #{same-bin keys > k} -- exact (bins monotone in masked
// key score; same bin resolved by full u64 compare over the bin's bucket).
// Keys unique => rank bijects onto the (score desc, idx asc) sorted order.

__global__ __launch_bounds__(256) void k_rankprep(
    const uint64_t* __restrict__ packed, const uint32_t* __restrict__ bcnt,
    const uint64_t* __restrict__ bucket,
    const int* __restrict__ classes,
    const float* __restrict__ r0, const float* __restrict__ r1, const float* __restrict__ r2,
    const float* __restrict__ r3, const float* __restrict__ r4,
    double4* __restrict__ rawbox, float* __restrict__ clsall,
    float* __restrict__ outs, float* __restrict__ outc, float* __restrict__ outb,
    uint64_t* __restrict__ keepw, unsigned long long* __restrict__ pmaxE)
{
    __shared__ uint32_t lh[2048];
    __shared__ uint32_t chs[64];
    __shared__ uint32_t chsuf[64];   // strictly-above chunk suffix sums
    __shared__ uint64_t pass[512];
    __shared__ double redw[4];
    __shared__ int sB, sNP;
    int blk = blockIdx.x;
    int b = blk >> 5, g = blk & 31;
    int tid = threadIdx.x;
    int lane = tid & 63, wid = tid >> 6;
    const uint64_t* pk = packed + (size_t)b * PPAD;

    for (int t = tid; t < 2048; t += 256) lh[t] = bcnt[b * 2048 + t];
    if (tid == 0) sNP = 0;
    __syncthreads();

    if (tid < 64) {
        uint32_t ss = 0;
        for (int i = 0; i < 32; ++i) ss += lh[tid * 32 + i];
        chs[tid] = ss;
    }
    __syncthreads();
    if (wid == 0) {
        // reversed inclusive prefix P(l) = sum chs[63-l .. 63]
        uint32_t v = chs[63 - lane];
        uint32_t P = v;
        for (int d = 1; d < 64; d <<= 1) {
            uint32_t u = __shfl_up(P, d, 64);
            if (lane >= d) P += u;
        }
        chsuf[63 - lane] = P - v;              // strictly above chunk 63-lane
        uint64_t bal = __ballot(P >= 1024u);
        int lstar = __builtin_ctzll(bal);
        int cstar = 63 - lstar;
        uint32_t Pst = (uint32_t)__shfl((int)P, lstar, 64);
        uint32_t C1c = Pst - chs[cstar];
        uint32_t w = (lane < 32) ? lh[cstar * 32 + 31 - lane] : 0u;
        uint32_t Q = w;
        for (int d = 1; d < 32; d <<= 1) {
            uint32_t u = __shfl_up(Q, d, 64);
            if (lane >= d) Q += u;
        }
        uint64_t bal2 = __ballot((lane < 32) && (C1c + Q >= 1024u));
        int l2 = __builtin_ctzll(bal2);
        if (lane == 0) sB = cstar * 32 + 31 - l2;
    }
    __syncthreads();
    int B = sB;

    // extract this block's slice passers (512 keys -> 2 iterations)
    int src0 = g * 512;
#pragma unroll
    for (int k = 0; k < 2; ++k) {
        uint64_t key = pk[src0 + tid + k * 256];
        bool pred = (key != 0ull) && (val_bin(key_score(key)) >= B);
        uint64_t bal = __ballot(pred);
        int bs = 0;
        if (lane == 0 && bal) bs = atomicAdd(&sNP, (int)__popcll(bal));
        bs = __shfl(bs, 0, 64);
        if (pred) pass[bs + __popcll(bal & ((1ull << lane) - 1ull))] = key;
    }
    __syncthreads();
    int np = sNP;

    // per-passer analytic rank + gather (one passer per thread)
    double lm = -1e300;
    if (tid < np) {
        uint64_t key = pass[tid];
        double s = key_score(key);
        int bin = val_bin(s);
        int c = bin >> 5;
        uint32_t rank = chsuf[c];
        for (int j = bin + 1; j < (c + 1) * 32; ++j) rank += lh[j];
        uint32_t bc = bcnt[b * 2048 + bin];
        if (bc <= BCAP) {
            const uint64_t* bk = bucket + ((size_t)b * 2048 + bin) * BCAP;
            for (uint32_t i = 0; i < bc; ++i) rank += (bk[i] > key) ? 1u : 0u;
        } else {
            // exact fallback (never taken for this data): scan whole batch
            for (int t2 = 0; t2 < PPAD; ++t2) {
                uint64_t k2 = pk[t2];
                if (k2 > key && val_bin(key_score(k2)) == bin) ++rank;
            }
        }

        if (rank < 1024u) {
            int idx = 0x3FFF - (int)(key & 0x3FFF);
            idx = idx < 0 ? 0 : (idx > P_TOTAL - 1 ? P_TOTAL - 1 : idx);

            int base2, w2, hw, st;
            const float* reg;
            if (idx < 10000)      { base2 = 0;     w2 = 100; hw = 10000; st = 8;   reg = r0; }
            else if (idx < 12500) { base2 = 10000; w2 = 50;  hw = 2500;  st = 16;  reg = r1; }
            else if (idx < 13125) { base2 = 12500; w2 = 25;  hw = 625;   st = 32;  reg = r2; }
            else if (idx < 13294) { base2 = 13125; w2 = 13;  hw = 169;   st = 64;  reg = r3; }
            else                  { base2 = 13294; w2 = 7;   hw = 49;    st = 128; reg = r4; }
            int yx = idx - base2;
            int y = yx / w2;
            int x = yx - y * w2;
            double sx = (double)(x * st + st / 2);
            double sy = (double)(y * st + st / 2);
            const float* rp = reg + (size_t)b * 4 * hw + yx;
            double x1 = sx - (double)rp[0];
            double y1 = sy - (double)rp[hw];
            double x2 = sx + (double)rp[2 * (size_t)hw];
            double y2 = sy + (double)rp[3 * (size_t)hw];
            int cv = classes[(size_t)b * P_TOTAL + idx];

            bool valid = (rank < KTOP) && (s >= D_SCORE_THR);
            size_t ix = (size_t)b * 1024 + rank;
            rawbox[ix] = make_double4(x1, y1, x2, y2);
            clsall[ix] = (float)cv;
            if (rank < KTOP) {
                outs[ix] = (float)s;
                outc[ix] = (float)cv;
                ((float4*)outb)[ix] = make_float4((float)x1, (float)y1,
                                                  (float)x2, (float)y2);
                // reference: max over where(valid, coords, 0.0)
                lm = valid ? fmax(fmax(x1, y1), fmax(x2, y2)) : 0.0;
            }
            if (valid)
                atomicOr((unsigned long long*)&keepw[(size_t)b * 16 + (rank >> 6)],
                         1ull << (rank & 63));
        }
    }

    // block fmax reduce (exact) -> one atomicMax per block
    for (int d = 1; d < 64; d <<= 1)
        lm = fmax(lm, __shfl_xor(lm, d, 64));
    if (lane == 0) redw[wid] = lm;
    __syncthreads();
    if (tid == 0) {
        double mm = fmax(fmax(redw[0], redw[1]), fmax(redw[2], redw[3]));
        atomicMax(&pmaxE[b], enc64(mm));
    }
}

// ---------------- S2: mask matrix from staged boxes (coalesced) -----------------

__global__ __launch_bounds__(256) void k_mask(
    const double4* __restrict__ rawbox, const float* __restrict__ clsall,
    const unsigned long long* __restrict__ pmaxE,
    uint64_t* __restrict__ M, uint64_t* __restrict__ D,
    uint32_t* __restrict__ Rnz)
{
    __shared__ double lx1[1024], ly1[1024], lx2[1024], ly2[1024], lar[1024];
    __shared__ float4 fbox[1024];
    __shared__ uint64_t ornz[4][64];
    int bid = blockIdx.x;
    int b = bid >> 4, rb = bid & 15;
    int tid = threadIdx.x;

    double offscale = dec64(pmaxE[b]) + 1.0;

    for (int t = tid; t < 1024; t += 256) {
        size_t ix = (size_t)b * 1024 + t;
        double4 rb4 = rawbox[ix];
        double o = (double)clsall[ix] * offscale;
        double ox1 = rb4.x + o, oy1 = rb4.y + o;
        double ox2 = rb4.z + o, oy2 = rb4.w + o;
        lx1[t] = ox1; ly1[t] = oy1; lx2[t] = ox2; ly2[t] = oy2;
        lar[t] = (ox2 - ox1 + 1.0) * (oy2 - oy1 + 1.0);
        fbox[t] = make_float4((float)ox1, (float)oy1, (float)ox2, (float)oy2);
    }
    __syncthreads();

    int ww = tid >> 6;
    int l  = tid & 63;
    int r  = rb * 64 + l;
    float4 fr = fbox[r];
    double rx1 = lx1[r], ry1 = ly1[r], rx2 = lx2[r], ry2 = ly2[r], ra = lar[r];
    int wbase = ww * 4;

    uint64_t bits0 = 0, bits1 = 0, bits2 = 0, bits3 = 0;

#define COLWORD(Q, BITS)                                                       \
    {                                                                          \
        int cb = (wbase + (Q)) * 64;                                           \
        if (cb + 63 > r) {                                                     \
            for (int kk = 0; kk < 64; ++kk) {                                  \
                int j = cb + kk;                                               \
                float4 fb = fbox[j];                                           \
                float xm = fminf(fb.z, fr.z) - fmaxf(fb.x, fr.x);              \
                float ym = fminf(fb.w, fr.w) - fmaxf(fb.y, fr.y);              \
                if (xm > -0.5f && ym > -0.5f) {                                \
                    double xmn = fmax(lx1[j], rx1);                            \
                    double ymn = fmax(ly1[j], ry1);                            \
                    double xmx = fmin(lx2[j], rx2);                            \
                    double ymx = fmin(ly2[j], ry2);                            \
                    double iw = xmx - xmn; iw = iw < 0.0 ? 0.0 : iw;           \
                    double ih = ymx - ymn; ih = ih < 0.0 ? 0.0 : ih;           \
                    double inter = iw * ih;                                    \
                    double iou = inter / (ra + lar[j] - inter);                \
                    BITS |= ((uint64_t)((j > r) && (iou > D_IOU_THR))) << kk;  \
                }                                                              \
            }                                                                  \
        }                                                                      \
    }

    COLWORD(0, bits0) COLWORD(1, bits1) COLWORD(2, bits2) COLWORD(3, bits3)
#undef COLWORD

    size_t mrow = ((size_t)b * 1024 + r) * 16 + wbase;
    M[mrow + 0] = bits0; M[mrow + 1] = bits1;
    M[mrow + 2] = bits2; M[mrow + 3] = bits3;

    if (ww == (rb >> 2)) {
        uint64_t db = (rb & 3) == 0 ? bits0 : (rb & 3) == 1 ? bits1
                    : (rb & 3) == 2 ? bits2 : bits3;
        D[((size_t)b * 16 + rb) * 64 + l] = db;
    }

    ornz[ww][l] = bits0 | bits1 | bits2 | bits3;
    __syncthreads();
    if (ww == 0) {
        uint64_t o = ornz[0][l] | ornz[1][l] | ornz[2][l] | ornz[3][l];
        Rnz[(size_t)b * 1024 + r] = (o != 0) ? 1u : 0u;
    }
}

// ---------------- S3: one-wave sparse scan ----------------

#define LOADC(G)                                                               \
    C0  = Mb[((size_t)(G) * 64 +  0 + p) * 16 + w];                            \
    C1  = Mb[((size_t)(G) * 64 +  4 + p) * 16 + w];                            \
    C2  = Mb[((size_t)(G) * 64 +  8 + p) * 16 + w];                            \
    C3  = Mb[((size_t)(G) * 64 + 12 + p) * 16 + w];                            \
    C4  = Mb[((size_t)(G) * 64 + 16 + p) * 16 + w];                            \
    C5  = Mb[((size_t)(G) * 64 + 20 + p) * 16 + w];                            \
    C6  = Mb[((size_t)(G) * 64 + 24 + p) * 16 + w];                            \
    C7  = Mb[((size_t)(G) * 64 + 28 + p) * 16 + w];                            \
    C8  = Mb[((size_t)(G) * 64 + 32 + p) * 16 + w];                            \
    C9  = Mb[((size_t)(G) * 64 + 36 + p) * 16 + w];                            \
    C10 = Mb[((size_t)(G) * 64 + 40 + p) * 16 + w];                            \
    C11 = Mb[((size_t)(G) * 64 + 44 + p) * 16 + w];                            \
    C12 = Mb[((size_t)(G) * 64 + 48 + p) * 16 + w];                            \
    C13 = Mb[((size_t)(G) * 64 + 52 + p) * 16 + w];                            \
    C14 = Mb[((size_t)(G) * 64 + 56 + p) * 16 + w];                            \
    C15 = Mb[((size_t)(G) * 64 + 60 + p) * 16 + w];

#define APPLY_Q(q)                                                             \
    {                                                                          \
        uint64_t t_ = (alive >> (4 * (q) + p)) & 1ull;                         \
        acc &= ~(C##q & (0ull - t_));                                          \
    }

#define STEPG(G)                                                               \
    {                                                                          \
        uint64_t kg = rl64(kw, (G));                                           \
        if (kg & nz##G) {                                                      \
            uint64_t dg = Dp[(size_t)(G) * 64 + lane];                         \
            LOADC(G)                                                           \
            uint64_t cur = kg, it = kg & nz##G;                                \
            while (it) {                                                       \
                int kk = __builtin_ctzll(it);                                  \
                uint64_t dk = rl64(dg, kk);                                    \
                cur &= ~dk;                                                    \
                it &= ~dk;                                                     \
                it &= it - 1ull;                                               \
            }                                                                  \
            uint64_t alive = cur;                                              \
            uint64_t acc = ~0ull;                                              \
            APPLY_Q(0)  APPLY_Q(1)  APPLY_Q(2)  APPLY_Q(3)                     \
            APPLY_Q(4)  APPLY_Q(5)  APPLY_Q(6)  APPLY_Q(7)                     \
            APPLY_Q(8)  APPLY_Q(9)  APPLY_Q(10) APPLY_Q(11)                    \
            APPLY_Q(12) APPLY_Q(13) APPLY_Q(14) APPLY_Q(15)                    \
            acc &= __shfl_xor(acc, 16, 64);                                    \
            acc &= __shfl_xor(acc, 32, 64);                                    \
            kw &= acc;                                                         \
        }                                                                      \
    }

__global__ __launch_bounds__(64, 1) void k_scan(
    const uint64_t* __restrict__ M, const uint64_t* __restrict__ D,
    const uint32_t* __restrict__ Rnz, const uint64_t* __restrict__ keepw,
    const float* __restrict__ outs, const float* __restrict__ outc,
    const float* __restrict__ outb, float* __restrict__ out)
{
    int b = blockIdx.x;
    int lane = threadIdx.x;          // one wave
    int p = (lane >> 4) & 3;         // replica 0..3
    int w = lane & 15;               // word index
    const uint64_t* Mb = M + (size_t)b * 1024 * 16;
    const uint64_t* Dp = D + (size_t)b * 1024;
    const uint32_t* Rp = Rnz + (size_t)b * 1024;

    uint64_t kw = keepw[(size_t)b * 16 + w];   // word w, replicated x4

    uint32_t f0  = Rp[0 * 64 + lane],  f1  = Rp[1 * 64 + lane];
    uint32_t f2  = Rp[2 * 64 + lane],  f3  = Rp[3 * 64 + lane];
    uint32_t f4  = Rp[4 * 64 + lane],  f5  = Rp[5 * 64 + lane];
    uint32_t f6  = Rp[6 * 64 + lane],  f7  = Rp[7 * 64 + lane];
    uint32_t f8  = Rp[8 * 64 + lane],  f9  = Rp[9 * 64 + lane];
    uint32_t f10 = Rp[10 * 64 + lane], f11 = Rp[11 * 64 + lane];
    uint32_t f12 = Rp[12 * 64 + lane], f13 = Rp[13 * 64 + lane];
    uint32_t f14 = Rp[14 * 64 + lane], f15 = Rp[15 * 64 + lane];
    uint64_t nz0  = __ballot(f0 != 0),  nz1  = __ballot(f1 != 0);
    uint64_t nz2  = __ballot(f2 != 0),  nz3  = __ballot(f3 != 0);
    uint64_t nz4  = __ballot(f4 != 0),  nz5  = __ballot(f5 != 0);
    uint64_t nz6  = __ballot(f6 != 0),  nz7  = __ballot(f7 != 0);
    uint64_t nz8  = __ballot(f8 != 0),  nz9  = __ballot(f9 != 0);
    uint64_t nz10 = __ballot(f10 != 0), nz11 = __ballot(f11 != 0);
    uint64_t nz12 = __ballot(f12 != 0), nz13 = __ballot(f13 != 0);
    uint64_t nz14 = __ballot(f14 != 0), nz15 = __ballot(f15 != 0);

    uint64_t C0,C1,C2,C3,C4,C5,C6,C7,C8,C9,C10,C11,C12,C13,C14,C15;

    STEPG(0)  STEPG(1)  STEPG(2)  STEPG(3)
    STEPG(4)  STEPG(5)  STEPG(6)  STEPG(7)
    STEPG(8)  STEPG(9)  STEPG(10) STEPG(11)
    STEPG(12) STEPG(13) STEPG(14) STEPG(15)

#pragma unroll
    for (int t = 0; t < 16; ++t) {
        int j = t * 64 + lane;
        uint64_t kwt = rl64(kw, t);
        bool kp = (kwt >> lane) & 1ull;
        if (j < KTOP) {
            size_t ix = (size_t)b * 1024 + j;
            out[(size_t)b * KTOP + j] = kp ? outs[ix] : 0.0f;
            out[(size_t)NB * KTOP + (size_t)b * KTOP + j] = kp ? outc[ix] : 0.0f;
            float4 bb = kp ? ((const float4*)outb)[ix] : make_float4(0.f, 0.f, 0.f, 0.f);
            ((float4*)(out + 2 * (size_t)NB * KTOP))[(size_t)b * KTOP + j] = bb;
        }
    }
}

// ---------------- launch ----------------

extern "C" void kernel_launch(void* const* d_in, const int* in_sizes, int n_in,
                              void* d_out, int out_size, void* d_ws, size_t ws_size,
                              hipStream_t stream) {
    const float* cls[5];
    const float* cnt[5];
    const float* reg[5];
    for (int i = 0; i < 5; ++i) {
        cls[i] = (const float*)d_in[i];
        cnt[i] = (const float*)d_in[5 + i];
        reg[i] = (const float*)d_in[10 + i];
    }
    float* out = (float*)d_out;

    // ws layout (bytes); M reuses the packed region (packed dead after k_rankprep)
    char* ws = (char*)d_ws;
    uint64_t* packed  = (uint64_t*)(ws + 0);          // 1,048,576
    uint64_t* M       = (uint64_t*)(ws + 0);          // 1,048,576 (reuse)
    int*      classes = (int*)     (ws + 1048576);    // 426,976 -> 1,475,552
    uint32_t* bcnt    = (uint32_t*)(ws + 1541088);    // 65,536  -> 1,606,624
    uint64_t* bucket  = (uint64_t*)(ws + 1606624);    // 33,554,432 -> 35,161,056
    double4*  rawbox  = (double4*) (ws + 35161056);   // 262,144 (32B aligned) -> 35,423,200
    float*    clsall  = (float*)   (ws + 35423200);   // 32,768 -> 35,455,968
    unsigned long long* pmaxE = (unsigned long long*)(ws + 35455968);  // 64 -> 35,456,032
    uint64_t* keepw   = (uint64_t*)(ws + 35456032);   // 1,024 -> 35,457,056
    uint64_t* D       = (uint64_t*)(ws + 35457056);   // 65,536 -> 35,522,592
    uint32_t* Rnz     = (uint32_t*)(ws + 35522592);   // 32,768 -> 35,555,360
    float*    outs    = (float*)   (ws + 35555360);   // 32,768 -> 35,588,128
    float*    outc    = (float*)   (ws + 35588128);   // 32,768 -> 35,620,896
    float*    outb    = (float*)   (ws + 35620896);   // 131,072 (16B aligned) -> 35,751,968

    k_zero<<<64, 256, 0, stream>>>(bcnt, keepw, pmaxE);

    k_scores<<<(NB * PPAD) / 256, 256, 0, stream>>>(
        cls[0], cls[1], cls[2], cls[3], cls[4],
        cnt[0], cnt[1], cnt[2], cnt[3], cnt[4],
        packed, classes, bcnt, bucket);

    k_rankprep<<<NB * 32, 256, 0, stream>>>(packed, bcnt, bucket, classes,
                                            reg[0], reg[1], reg[2], reg[3], reg[4],
                                            rawbox, clsall, outs, outc, outb,
                                            keepw, pmaxE);

    k_mask<<<NB * 16, 256, 0, stream>>>(rawbox, clsall, pmaxE, M, D, Rnz);

    k_scan<<<NB, 64, 0, stream>>>(M, D, Rnz, keepw, outs, outc, outb, out);
}

// Round 17
// 69.166 us; speedup vs baseline: 6.8863x; 1.1440x over previous
//
#include <hip/hip_runtime.h>
#include <math.h>
#include <stdint.h>

#define NB 8
#define P_TOTAL 13343
#define NCLS 80
#define KTOP 1000
#define PPAD 16384
#define BCAP 256
#define D_SCORE_THR 0.05
#define D_IOU_THR 0.6

// ---------------- helpers ----------------

__device__ __forceinline__ double sig64(double x) {
    if (x >= 0.0) {
        double e = exp(-x);
        return 1.0 / (1.0 + e);
    } else {
        double e = exp(x);
        return e / (1.0 + e);
    }
}

// key = score bits (top 50) | (0x3FFF - idx): descending order => score desc, idx asc
__device__ __forceinline__ uint64_t pack_key(double s, int p) {
    uint64_t b = (uint64_t)__double_as_longlong(s);
    return (b & ~0x3FFFull) | (uint64_t)(0x3FFF - p);
}

__device__ __forceinline__ double key_score(uint64_t key) {
    return __longlong_as_double((long long)(key & ~0x3FFFull));
}

__device__ __forceinline__ int val_bin(double s) {
    int bin = (int)(s * 2048.0);
    return bin < 0 ? 0 : (bin > 2047 ? 2047 : bin);
}

__device__ __forceinline__ uint64_t rl64(uint64_t v, int l) {
    uint32_t lo = (uint32_t)__builtin_amdgcn_readlane((int)(uint32_t)v, l);
    uint32_t hi = (uint32_t)__builtin_amdgcn_readlane((int)(uint32_t)(v >> 32), l);
    return ((uint64_t)hi << 32) | lo;
}

// order-preserving double -> u64 encoding (for atomicMax)
__device__ __forceinline__ unsigned long long enc64(double x) {
    long long u = __double_as_longlong(x);
    return (unsigned long long)(u < 0 ? ~u : (u | 0x8000000000000000ll));
}
__device__ __forceinline__ double dec64(unsigned long long e) {
    long long u = (e >> 63) ? (long long)(e & 0x7FFFFFFFFFFFFFFFull) : ~(long long)e;
    return __longlong_as_double(u);
}

// ---------------- S-1: zero scratch ----------------

__global__ __launch_bounds__(256) void k_zero(
    uint32_t* __restrict__ bcnt, uint32_t* __restrict__ Rnz,
    uint64_t* __restrict__ keepw, unsigned long long* __restrict__ pmaxE)
{
    int gid = blockIdx.x * 256 + threadIdx.x;
    if (gid < NB * 2048) bcnt[gid] = 0;                       // 16384 u32
    else if (gid < NB * 2048 + NB * 1024) Rnz[gid - NB * 2048] = 0;  // 8192 u32
    if (blockIdx.x == 0) {
        if (threadIdx.x < 128) keepw[threadIdx.x] = 0ull;
        else if (threadIdx.x < 136) pmaxE[threadIdx.x - 128] = 0ull;
    }
}

// ---------------- S0: scores/classes -> keys + bin counts + buckets -------------

__global__ __launch_bounds__(256) void k_scores(
    const float* __restrict__ c0, const float* __restrict__ c1, const float* __restrict__ c2,
    const float* __restrict__ c3, const float* __restrict__ c4,
    const float* __restrict__ n0, const float* __restrict__ n1, const float* __restrict__ n2,
    const float* __restrict__ n3, const float* __restrict__ n4,
    uint64_t* __restrict__ packed, int* __restrict__ classes,
    uint32_t* __restrict__ bcnt, uint64_t* __restrict__ bucket)
{
    int tid = threadIdx.x;
    int gid = blockIdx.x * 256 + tid;
    if (gid >= NB * PPAD) return;
    int b = gid >> 14;
    int p = gid & (PPAD - 1);
    if (p >= P_TOTAL) { packed[gid] = 0; return; }

    int base, hw;
    const float* cls;
    const float* cnt;
    if (p < 10000)      { base = 0;     hw = 10000; cls = c0; cnt = n0; }
    else if (p < 12500) { base = 10000; hw = 2500;  cls = c1; cnt = n1; }
    else if (p < 13125) { base = 12500; hw = 625;   cls = c2; cnt = n2; }
    else if (p < 13294) { base = 13125; hw = 169;   cls = c3; cnt = n3; }
    else                { base = 13294; hw = 49;    cls = c4; cnt = n4; }
    int yx = p - base;

    // argmax over 80 logits; two 40-chains for ILP; first-max ties preserved.
    const float* cp = cls + (size_t)b * NCLS * hw + yx;
    float m0 = -3.4e38f, m1 = -3.4e38f;
    int a0 = 0, a1 = 40;
    for (int c = 0; c < 40; ++c) {
        float v0 = cp[(size_t)c * hw];
        float v1 = cp[(size_t)(c + 40) * hw];
        if (v0 > m0) { m0 = v0; a0 = c; }
        if (v1 > m1) { m1 = v1; a1 = c + 40; }
    }
    float m = m0; int am = a0;
    if (m1 > m0) { m = m1; am = a1; }

    float cv = cnt[(size_t)b * hw + yx];
    double s = sqrt(sig64((double)m) * sig64((double)cv));

    uint64_t key = pack_key(s, p);
    packed[gid] = key;
    classes[(size_t)b * P_TOTAL + p] = am + 1;

    // single atomic: bucket slot counter doubles as the histogram (validated R15)
    int bn = val_bin(key_score(key));
    uint32_t slot = atomicAdd(&bcnt[b * 2048 + bn], 1u);
    if (slot < BCAP)
        bucket[((size_t)b * 2048 + bn) * BCAP + slot] = key;
}

// ---------------- S1: analytic-rank select+prep (verified R14/R16 body) ---------

__global__ __launch_bounds__(256) void k_rankprep(
    const uint64_t* __restrict__ packed, const uint32_t* __restrict__ bcnt,
    const uint64_t* __restrict__ bucket,
    const int* __restrict__ classes,
    const float* __restrict__ r0, const float* __restrict__ r1, const float* __restrict__ r2,
    const float* __restrict__ r3, const float* __restrict__ r4,
    double4* __restrict__ rawbox, float* __restrict__ clsall,
    float* __restrict__ outs, float* __restrict__ outc, float* __restrict__ outb,
    uint64_t* __restrict__ keepw, unsigned long long* __restrict__ pmaxE)
{
    __shared__ uint32_t lh[2048];
    __shared__ uint32_t chs[64];
    __shared__ uint32_t chsuf[64];
    __shared__ uint64_t pass[512];
    __shared__ double redw[4];
    __shared__ int sB, sNP;
    int blk = blockIdx.x;
    int b = blk >> 5, g = blk & 31;
    int tid = threadIdx.x;
    int lane = tid & 63, wid = tid >> 6;
    const uint64_t* pk = packed + (size_t)b * PPAD;

    for (int t = tid; t < 2048; t += 256) lh[t] = bcnt[b * 2048 + t];
    if (tid == 0) sNP = 0;
    __syncthreads();

    if (tid < 64) {
        uint32_t ss = 0;
        for (int i = 0; i < 32; ++i) ss += lh[tid * 32 + i];
        chs[tid] = ss;
    }
    __syncthreads();
    if (wid == 0) {
        uint32_t v = chs[63 - lane];
        uint32_t P = v;
        for (int d = 1; d < 64; d <<= 1) {
            uint32_t u = __shfl_up(P, d, 64);
            if (lane >= d) P += u;
        }
        chsuf[63 - lane] = P - v;
        uint64_t bal = __ballot(P >= 1024u);
        int lstar = __builtin_ctzll(bal);
        int cstar = 63 - lstar;
        uint32_t Pst = (uint32_t)__shfl((int)P, lstar, 64);
        uint32_t C1c = Pst - chs[cstar];
        uint32_t w = (lane < 32) ? lh[cstar * 32 + 31 - lane] : 0u;
        uint32_t Q = w;
        for (int d = 1; d < 32; d <<= 1) {
            uint32_t u = __shfl_up(Q, d, 64);
            if (lane >= d) Q += u;
        }
        uint64_t bal2 = __ballot((lane < 32) && (C1c + Q >= 1024u));
        int l2 = __builtin_ctzll(bal2);
        if (lane == 0) sB = cstar * 32 + 31 - l2;
    }
    __syncthreads();
    int B = sB;

    int src0 = g * 512;
#pragma unroll
    for (int k = 0; k < 2; ++k) {
        uint64_t key = pk[src0 + tid + k * 256];
        bool pred = (key != 0ull) && (val_bin(key_score(key)) >= B);
        uint64_t bal = __ballot(pred);
        int bs = 0;
        if (lane == 0 && bal) bs = atomicAdd(&sNP, (int)__popcll(bal));
        bs = __shfl(bs, 0, 64);
        if (pred) pass[bs + __popcll(bal & ((1ull << lane) - 1ull))] = key;
    }
    __syncthreads();
    int np = sNP;

    double lm = -1e300;
    if (tid < np) {
        uint64_t key = pass[tid];
        double s = key_score(key);
        int bin = val_bin(s);
        int c = bin >> 5;
        uint32_t rank = chsuf[c];
        for (int j = bin + 1; j < (c + 1) * 32; ++j) rank += lh[j];
        uint32_t bc = bcnt[b * 2048 + bin];
        if (bc <= BCAP) {
            const uint64_t* bk = bucket + ((size_t)b * 2048 + bin) * BCAP;
            for (uint32_t i = 0; i < bc; ++i) rank += (bk[i] > key) ? 1u : 0u;
        } else {
            for (int t2 = 0; t2 < PPAD; ++t2) {   // exact fallback (never taken)
                uint64_t k2 = pk[t2];
                if (k2 > key && val_bin(key_score(k2)) == bin) ++rank;
            }
        }

        if (rank < 1024u) {
            int idx = 0x3FFF - (int)(key & 0x3FFF);
            idx = idx < 0 ? 0 : (idx > P_TOTAL - 1 ? P_TOTAL - 1 : idx);

            int base2, w2, hw, st;
            const float* reg;
            if (idx < 10000)      { base2 = 0;     w2 = 100; hw = 10000; st = 8;   reg = r0; }
            else if (idx < 12500) { base2 = 10000; w2 = 50;  hw = 2500;  st = 16;  reg = r1; }
            else if (idx < 13125) { base2 = 12500; w2 = 25;  hw = 625;   st = 32;  reg = r2; }
            else if (idx < 13294) { base2 = 13125; w2 = 13;  hw = 169;   st = 64;  reg = r3; }
            else                  { base2 = 13294; w2 = 7;   hw = 49;    st = 128; reg = r4; }
            int yx = idx - base2;
            int y = yx / w2;
            int x = yx - y * w2;
            double sx = (double)(x * st + st / 2);
            double sy = (double)(y * st + st / 2);
            const float* rp = reg + (size_t)b * 4 * hw + yx;
            double x1 = sx - (double)rp[0];
            double y1 = sy - (double)rp[hw];
            double x2 = sx + (double)rp[2 * (size_t)hw];
            double y2 = sy + (double)rp[3 * (size_t)hw];
            int cv = classes[(size_t)b * P_TOTAL + idx];

            bool valid = (rank < KTOP) && (s >= D_SCORE_THR);
            size_t ix = (size_t)b * 1024 + rank;
            rawbox[ix] = make_double4(x1, y1, x2, y2);
            clsall[ix] = (float)cv;
            if (rank < KTOP) {
                outs[ix] = (float)s;
                outc[ix] = (float)cv;
                ((float4*)outb)[ix] = make_float4((float)x1, (float)y1,
                                                  (float)x2, (float)y2);
                lm = valid ? fmax(fmax(x1, y1), fmax(x2, y2)) : 0.0;
            }
            if (valid)
                atomicOr((unsigned long long*)&keepw[(size_t)b * 16 + (rank >> 6)],
                         1ull << (rank & 63));
        }
    }

    for (int d = 1; d < 64; d <<= 1)
        lm = fmax(lm, __shfl_xor(lm, d, 64));
    if (lane == 0) redw[wid] = lm;
    __syncthreads();
    if (tid == 0) {
        double mm = fmax(fmax(redw[0], redw[1]), fmax(redw[2], redw[3]));
        atomicMax(&pmaxE[b], enc64(mm));
    }
}

// ---------------- S2: mask matrix, split 2 blocks per row-block (256 blocks) ----
// block = (b, rb, h): h in {0,1} owns words h*8 .. h*8+7. Each wave does 2 words.
// Rnz accumulated via atomicOr (pre-zeroed in k_zero).

__global__ __launch_bounds__(256) void k_mask(
    const double4* __restrict__ rawbox, const float* __restrict__ clsall,
    const unsigned long long* __restrict__ pmaxE,
    uint64_t* __restrict__ M, uint64_t* __restrict__ D,
    uint32_t* __restrict__ Rnz)
{
    __shared__ double lx1[1024], ly1[1024], lx2[1024], ly2[1024], lar[1024];
    __shared__ float4 fbox[1024];
    int bid = blockIdx.x;
    int b = bid >> 5, rb = (bid >> 1) & 15, h = bid & 1;
    int tid = threadIdx.x;

    double offscale = dec64(pmaxE[b]) + 1.0;

    for (int t = tid; t < 1024; t += 256) {
        size_t ix = (size_t)b * 1024 + t;
        double4 rb4 = rawbox[ix];
        double o = (double)clsall[ix] * offscale;
        double ox1 = rb4.x + o, oy1 = rb4.y + o;
        double ox2 = rb4.z + o, oy2 = rb4.w + o;
        lx1[t] = ox1; ly1[t] = oy1; lx2[t] = ox2; ly2[t] = oy2;
        lar[t] = (ox2 - ox1 + 1.0) * (oy2 - oy1 + 1.0);
        fbox[t] = make_float4((float)ox1, (float)oy1, (float)ox2, (float)oy2);
    }
    __syncthreads();

    int ww = tid >> 6;            // wave 0..3
    int l  = tid & 63;            // lane = row
    int r  = rb * 64 + l;
    float4 fr = fbox[r];
    double rx1 = lx1[r], ry1 = ly1[r], rx2 = lx2[r], ry2 = ly2[r], ra = lar[r];
    int wbase = h * 8 + ww * 2;   // this thread's 2 words

    uint64_t bits0 = 0, bits1 = 0;

#define COLWORD(Q, BITS)                                                       \
    {                                                                          \
        int cb = (wbase + (Q)) * 64;                                           \
        if (cb + 63 > r) {                                                     \
            for (int kk = 0; kk < 64; ++kk) {                                  \
                int j = cb + kk;                                               \
                float4 fb = fbox[j];                                           \
                float xm = fminf(fb.z, fr.z) - fmaxf(fb.x, fr.x);              \
                float ym = fminf(fb.w, fr.w) - fmaxf(fb.y, fr.y);              \
                if (xm > -0.5f && ym > -0.5f) {                                \
                    double xmn = fmax(lx1[j], rx1);                            \
                    double ymn = fmax(ly1[j], ry1);                            \
                    double xmx = fmin(lx2[j], rx2);                            \
                    double ymx = fmin(ly2[j], ry2);                            \
                    double iw = xmx - xmn; iw = iw < 0.0 ? 0.0 : iw;           \
                    double ih = ymx - ymn; ih = ih < 0.0 ? 0.0 : ih;           \
                    double inter = iw * ih;                                    \
                    double iou = inter / (ra + lar[j] - inter);                \
                    BITS |= ((uint64_t)((j > r) && (iou > D_IOU_THR))) << kk;  \
                }                                                              \
            }                                                                  \
        }                                                                      \
    }

    COLWORD(0, bits0) COLWORD(1, bits1)
#undef COLWORD

    size_t mrow = ((size_t)b * 1024 + r) * 16 + wbase;
    M[mrow + 0] = bits0; M[mrow + 1] = bits1;

    // diagonal word (index rb): owned by block h==rb>>3, wave ww==(rb&7)>>1
    if (h == (rb >> 3) && ww == ((rb & 7) >> 1)) {
        uint64_t db = ((rb & 1) == 0) ? bits0 : bits1;
        D[((size_t)b * 16 + rb) * 64 + l] = db;
    }

    uint64_t orw = bits0 | bits1;
    if (orw) atomicOr(&Rnz[(size_t)b * 1024 + r], 1u);
}

// ---------------- S3: one-wave sparse scan (verified body) ----------------

#define LOADC(G)                                                               \
    C0  = Mb[((size_t)(G) * 64 +  0 + p) * 16 + w];                            \
    C1  = Mb[((size_t)(G) * 64 +  4 + p) * 16 + w];                            \
    C2  = Mb[((size_t)(G) * 64 +  8 + p) * 16 + w];                            \
    C3  = Mb[((size_t)(G) * 64 + 12 + p) * 16 + w];                            \
    C4  = Mb[((size_t)(G) * 64 + 16 + p) * 16 + w];                            \
    C5  = Mb[((size_t)(G) * 64 + 20 + p) * 16 + w];                            \
    C6  = Mb[((size_t)(G) * 64 + 24 + p) * 16 + w];                            \
    C7  = Mb[((size_t)(G) * 64 + 28 + p) * 16 + w];                            \
    C8  = Mb[((size_t)(G) * 64 + 32 + p) * 16 + w];                            \
    C9  = Mb[((size_t)(G) * 64 + 36 + p) * 16 + w];                            \
    C10 = Mb[((size_t)(G) * 64 + 40 + p) * 16 + w];                            \
    C11 = Mb[((size_t)(G) * 64 + 44 + p) * 16 + w];                            \
    C12 = Mb[((size_t)(G) * 64 + 48 + p) * 16 + w];                            \
    C13 = Mb[((size_t)(G) * 64 + 52 + p) * 16 + w];                            \
    C14 = Mb[((size_t)(G) * 64 + 56 + p) * 16 + w];                            \
    C15 = Mb[((size_t)(G) * 64 + 60 + p) * 16 + w];

#define APPLY_Q(q)                                                             \
    {                                                                          \
        uint64_t t_ = (alive >> (4 * (q) + p)) & 1ull;                         \
        acc &= ~(C##q & (0ull - t_));                                          \
    }

#define STEPG(G)                                                               \
    {                                                                          \
        uint64_t kg = rl64(kw, (G));                                           \
        if (kg & nz##G) {                                                      \
            uint64_t dg = Dp[(size_t)(G) * 64 + lane];                         \
            LOADC(G)                                                           \
            uint64_t cur = kg, it = kg & nz##G;                                \
            while (it) {                                                       \
                int kk = __builtin_ctzll(it);                                  \
                uint64_t dk = rl64(dg, kk);                                    \
                cur &= ~dk;                                                    \
                it &= ~dk;                                                     \
                it &= it - 1ull;                                               \
            }                                                                  \
            uint64_t alive = cur;                                              \
            uint64_t acc = ~0ull;                                              \
            APPLY_Q(0)  APPLY_Q(1)  APPLY_Q(2)  APPLY_Q(3)                     \
            APPLY_Q(4)  APPLY_Q(5)  APPLY_Q(6)  APPLY_Q(7)                     \
            APPLY_Q(8)  APPLY_Q(9)  APPLY_Q(10) APPLY_Q(11)                    \
            APPLY_Q(12) APPLY_Q(13) APPLY_Q(14) APPLY_Q(15)                    \
            acc &= __shfl_xor(acc, 16, 64);                                    \
            acc &= __shfl_xor(acc, 32, 64);                                    \
            kw &= acc;                                                         \
        }                                                                      \
    }

__global__ __launch_bounds__(64, 1) void k_scan(
    const uint64_t* __restrict__ M, const uint64_t* __restrict__ D,
    const uint32_t* __restrict__ Rnz, const uint64_t* __restrict__ keepw,
    const float* __restrict__ outs, const float* __restrict__ outc,
    const float* __restrict__ outb, float* __restrict__ out)
{
    int b = blockIdx.x;
    int lane = threadIdx.x;          // one wave
    int p = (lane >> 4) & 3;         // replica 0..3
    int w = lane & 15;               // word index
    const uint64_t* Mb = M + (size_t)b * 1024 * 16;
    const uint64_t* Dp = D + (size_t)b * 1024;
    const uint32_t* Rp = Rnz + (size_t)b * 1024;

    uint64_t kw = keepw[(size_t)b * 16 + w];   // word w, replicated x4

    uint32_t f0  = Rp[0 * 64 + lane],  f1  = Rp[1 * 64 + lane];
    uint32_t f2  = Rp[2 * 64 + lane],  f3  = Rp[3 * 64 + lane];
    uint32_t f4  = Rp[4 * 64 + lane],  f5  = Rp[5 * 64 + lane];
    uint32_t f6  = Rp[6 * 64 + lane],  f7  = Rp[7 * 64 + lane];
    uint32_t f8  = Rp[8 * 64 + lane],  f9  = Rp[9 * 64 + lane];
    uint32_t f10 = Rp[10 * 64 + lane], f11 = Rp[11 * 64 + lane];
    uint32_t f12 = Rp[12 * 64 + lane], f13 = Rp[13 * 64 + lane];
    uint32_t f14 = Rp[14 * 64 + lane], f15 = Rp[15 * 64 + lane];
    uint64_t nz0  = __ballot(f0 != 0),  nz1  = __ballot(f1 != 0);
    uint64_t nz2  = __ballot(f2 != 0),  nz3  = __ballot(f3 != 0);
    uint64_t nz4  = __ballot(f4 != 0),  nz5  = __ballot(f5 != 0);
    uint64_t nz6  = __ballot(f6 != 0),  nz7  = __ballot(f7 != 0);
    uint64_t nz8  = __ballot(f8 != 0),  nz9  = __ballot(f9 != 0);
    uint64_t nz10 = __ballot(f10 != 0), nz11 = __ballot(f11 != 0);
    uint64_t nz12 = __ballot(f12 != 0), nz13 = __ballot(f13 != 0);
    uint64_t nz14 = __ballot(f14 != 0), nz15 = __ballot(f15 != 0);

    uint64_t C0,C1,C2,C3,C4,C5,C6,C7,C8,C9,C10,C11,C12,C13,C14,C15;

    STEPG(0)  STEPG(1)  STEPG(2)  STEPG(3)
    STEPG(4)  STEPG(5)  STEPG(6)  STEPG(7)
    STEPG(8)  STEPG(9)  STEPG(10) STEPG(11)
    STEPG(12) STEPG(13) STEPG(14) STEPG(15)

#pragma unroll
    for (int t = 0; t < 16; ++t) {
        int j = t * 64 + lane;
        uint64_t kwt = rl64(kw, t);
        bool kp = (kwt >> lane) & 1ull;
        if (j < KTOP) {
            size_t ix = (size_t)b * 1024 + j;
            out[(size_t)b * KTOP + j] = kp ? outs[ix] : 0.0f;
            out[(size_t)NB * KTOP + (size_t)b * KTOP + j] = kp ? outc[ix] : 0.0f;
            float4 bb = kp ? ((const float4*)outb)[ix] : make_float4(0.f, 0.f, 0.f, 0.f);
            ((float4*)(out + 2 * (size_t)NB * KTOP))[(size_t)b * KTOP + j] = bb;
        }
    }
}

// ---------------- launch ----------------

extern "C" void kernel_launch(void* const* d_in, const int* in_sizes, int n_in,
                              void* d_out, int out_size, void* d_ws, size_t ws_size,
                              hipStream_t stream) {
    const float* cls[5];
    const float* cnt[5];
    const float* reg[5];
    for (int i = 0; i < 5; ++i) {
        cls[i] = (const float*)d_in[i];
        cnt[i] = (const float*)d_in[5 + i];
        reg[i] = (const float*)d_in[10 + i];
    }
    float* out = (float*)d_out;

    // ws layout (bytes); M reuses the packed region (packed dead after k_rankprep)
    char* ws = (char*)d_ws;
    uint64_t* packed  = (uint64_t*)(ws + 0);          // 1,048,576
    uint64_t* M       = (uint64_t*)(ws + 0);          // 1,048,576 (reuse)
    int*      classes = (int*)     (ws + 1048576);    // 426,976 -> 1,475,552
    uint32_t* bcnt    = (uint32_t*)(ws + 1541088);    // 65,536  -> 1,606,624
    uint64_t* bucket  = (uint64_t*)(ws + 1606624);    // 33,554,432 -> 35,161,056
    double4*  rawbox  = (double4*) (ws + 35161056);   // 262,144 (32B aligned) -> 35,423,200
    float*    clsall  = (float*)   (ws + 35423200);   // 32,768 -> 35,455,968
    unsigned long long* pmaxE = (unsigned long long*)(ws + 35455968);  // 64 -> 35,456,032
    uint64_t* keepw   = (uint64_t*)(ws + 35456032);   // 1,024 -> 35,457,056
    uint64_t* D       = (uint64_t*)(ws + 35457056);   // 65,536 -> 35,522,592
    uint32_t* Rnz     = (uint32_t*)(ws + 35522592);   // 32,768 -> 35,555,360
    float*    outs    = (float*)   (ws + 35555360);   // 32,768 -> 35,588,128
    float*    outc    = (float*)   (ws + 35588128);   // 32,768 -> 35,620,896
    float*    outb    = (float*)   (ws + 35620896);   // 131,072 (16B aligned) -> 35,751,968

    k_zero<<<96, 256, 0, stream>>>(bcnt, Rnz, keepw, pmaxE);

    k_scores<<<(NB * PPAD) / 256, 256, 0, stream>>>(
        cls[0], cls[1], cls[2], cls[3], cls[4],
        cnt[0], cnt[1], cnt[2], cnt[3], cnt[4],
        packed, classes, bcnt, bucket);

    k_rankprep<<<NB * 32, 256, 0, stream>>>(packed, bcnt, bucket, classes,
                                            reg[0], reg[1], reg[2], reg[3], reg[4],
                                            rawbox, clsall, outs, outc, outb,
                                            keepw, pmaxE);

    k_mask<<<NB * 32, 256, 0, stream>>>(rawbox, clsall, pmaxE, M, D, Rnz);

    k_scan<<<NB, 64, 0, stream>>>(M, D, Rnz, keepw, outs, outc, outb, out);
}

// Round 18
// 68.062 us; speedup vs baseline: 6.9980x; 1.0162x over previous
//
#include <hip/hip_runtime.h>
#include <math.h>
#include <stdint.h>

#define NB 8
#define P_TOTAL 13343
#define NCLS 80
#define KTOP 1000
#define PPAD 16384
#define BCAP 256
#define D_SCORE_THR 0.05
#define D_IOU_THR 0.6

// ---------------- helpers ----------------

__device__ __forceinline__ double sig64(double x) {
    if (x >= 0.0) {
        double e = exp(-x);
        return 1.0 / (1.0 + e);
    } else {
        double e = exp(x);
        return e / (1.0 + e);
    }
}

// key = score bits (top 50) | (0x3FFF - idx): descending order => score desc, idx asc
__device__ __forceinline__ uint64_t pack_key(double s, int p) {
    uint64_t b = (uint64_t)__double_as_longlong(s);
    return (b & ~0x3FFFull) | (uint64_t)(0x3FFF - p);
}

__device__ __forceinline__ double key_score(uint64_t key) {
    return __longlong_as_double((long long)(key & ~0x3FFFull));
}

__device__ __forceinline__ int val_bin(double s) {
    int bin = (int)(s * 2048.0);
    return bin < 0 ? 0 : (bin > 2047 ? 2047 : bin);
}

__device__ __forceinline__ uint64_t rl64(uint64_t v, int l) {
    uint32_t lo = (uint32_t)__builtin_amdgcn_readlane((int)(uint32_t)v, l);
    uint32_t hi = (uint32_t)__builtin_amdgcn_readlane((int)(uint32_t)(v >> 32), l);
    return ((uint64_t)hi << 32) | lo;
}

// order-preserving double -> u64 encoding (for atomicMax)
__device__ __forceinline__ unsigned long long enc64(double x) {
    long long u = __double_as_longlong(x);
    return (unsigned long long)(u < 0 ? ~u : (u | 0x8000000000000000ll));
}
__device__ __forceinline__ double dec64(unsigned long long e) {
    long long u = (e >> 63) ? (long long)(e & 0x7FFFFFFFFFFFFFFFull) : ~(long long)e;
    return __longlong_as_double(u);
}

// ---------------- S-1: zero bcnt only (tiny) ----------------

__global__ __launch_bounds__(256) void k_zero(uint32_t* __restrict__ bcnt)
{
    bcnt[blockIdx.x * 256 + threadIdx.x] = 0;   // 64 blocks x 256 = 16384
}

// ---------------- S0: scores -> keys + LDS-aggregated bin counts/buckets --------
// Blocks 0..511: main work (each block = 256 contiguous points of one batch).
// Block 512: zeroes Rnz/keepw/pmaxE (consumers run in later dispatches).

__global__ __launch_bounds__(256) void k_scores(
    const float* __restrict__ c0, const float* __restrict__ c1, const float* __restrict__ c2,
    const float* __restrict__ c3, const float* __restrict__ c4,
    const float* __restrict__ n0, const float* __restrict__ n1, const float* __restrict__ n2,
    const float* __restrict__ n3, const float* __restrict__ n4,
    uint64_t* __restrict__ packed, int* __restrict__ classes,
    uint32_t* __restrict__ bcnt, uint64_t* __restrict__ bucket,
    uint32_t* __restrict__ Rnz, uint64_t* __restrict__ keepw,
    unsigned long long* __restrict__ pmaxE)
{
    int tid = threadIdx.x;
    int bx = blockIdx.x;

    if (bx >= 512) {   // zero tail block
        for (int t = tid; t < NB * 1024; t += 256) Rnz[t] = 0;
        if (tid < 128) keepw[tid] = 0ull;
        else if (tid < 136) pmaxE[tid - 128] = 0ull;
        return;
    }

    __shared__ uint32_t lcnt[2048];
    __shared__ uint32_t gbase[2048];
    __shared__ uint32_t lofs[2048];

    for (int t = tid; t < 2048; t += 256) lcnt[t] = 0;
    __syncthreads();

    int gid = bx * 256 + tid;
    int b = gid >> 14;
    int p = gid & (PPAD - 1);
    bool active = (p < P_TOTAL);

    uint64_t key = 0;
    int bn = 0;
    if (active) {
        int base, hw;
        const float* cls;
        const float* cnt;
        if (p < 10000)      { base = 0;     hw = 10000; cls = c0; cnt = n0; }
        else if (p < 12500) { base = 10000; hw = 2500;  cls = c1; cnt = n1; }
        else if (p < 13125) { base = 12500; hw = 625;   cls = c2; cnt = n2; }
        else if (p < 13294) { base = 13125; hw = 169;   cls = c3; cnt = n3; }
        else                { base = 13294; hw = 49;    cls = c4; cnt = n4; }
        int yx = p - base;

        // argmax over 80 logits; two 40-chains for ILP; first-max ties preserved.
        const float* cp = cls + (size_t)b * NCLS * hw + yx;
        float m0 = -3.4e38f, m1 = -3.4e38f;
        int a0 = 0, a1 = 40;
        for (int c = 0; c < 40; ++c) {
            float v0 = cp[(size_t)c * hw];
            float v1 = cp[(size_t)(c + 40) * hw];
            if (v0 > m0) { m0 = v0; a0 = c; }
            if (v1 > m1) { m1 = v1; a1 = c + 40; }
        }
        float m = m0; int am = a0;
        if (m1 > m0) { m = m1; am = a1; }

        float cv = cnt[(size_t)b * hw + yx];
        double s = sqrt(sig64((double)m) * sig64((double)cv));

        key = pack_key(s, p);
        packed[gid] = key;
        classes[(size_t)b * P_TOTAL + p] = am + 1;

        bn = val_bin(key_score(key));
        atomicAdd(&lcnt[bn], 1u);          // cheap LDS atomic
    } else {
        packed[gid] = 0;
    }
    __syncthreads();

    // one global atomic per touched bin per block (<=64 contenders per bin)
    for (int t = tid; t < 2048; t += 256) {
        lofs[t] = 0;
        uint32_t c = lcnt[t];
        if (c) gbase[t] = atomicAdd(&bcnt[b * 2048 + t], c);
    }
    __syncthreads();

    if (active) {
        uint32_t off = atomicAdd(&lofs[bn], 1u);
        uint32_t slot = gbase[bn] + off;
        if (slot < BCAP)
            bucket[((size_t)b * 2048 + bn) * BCAP + slot] = key;
    }
}

// ---------------- S1: analytic-rank select+prep (verified R14/R16 body) ---------

__global__ __launch_bounds__(256) void k_rankprep(
    const uint64_t* __restrict__ packed, const uint32_t* __restrict__ bcnt,
    const uint64_t* __restrict__ bucket,
    const int* __restrict__ classes,
    const float* __restrict__ r0, const float* __restrict__ r1, const float* __restrict__ r2,
    const float* __restrict__ r3, const float* __restrict__ r4,
    double4* __restrict__ rawbox, float* __restrict__ clsall,
    float* __restrict__ outs, float* __restrict__ outc, float* __restrict__ outb,
    uint64_t* __restrict__ keepw, unsigned long long* __restrict__ pmaxE)
{
    __shared__ uint32_t lh[2048];
    __shared__ uint32_t chs[64];
    __shared__ uint32_t chsuf[64];
    __shared__ uint64_t pass[512];
    __shared__ double redw[4];
    __shared__ int sB, sNP;
    int blk = blockIdx.x;
    int b = blk >> 5, g = blk & 31;
    int tid = threadIdx.x;
    int lane = tid & 63, wid = tid >> 6;
    const uint64_t* pk = packed + (size_t)b * PPAD;

    for (int t = tid; t < 2048; t += 256) lh[t] = bcnt[b * 2048 + t];
    if (tid == 0) sNP = 0;
    __syncthreads();

    if (tid < 64) {
        uint32_t ss = 0;
        for (int i = 0; i < 32; ++i) ss += lh[tid * 32 + i];
        chs[tid] = ss;
    }
    __syncthreads();
    if (wid == 0) {
        uint32_t v = chs[63 - lane];
        uint32_t P = v;
        for (int d = 1; d < 64; d <<= 1) {
            uint32_t u = __shfl_up(P, d, 64);
            if (lane >= d) P += u;
        }
        chsuf[63 - lane] = P - v;
        uint64_t bal = __ballot(P >= 1024u);
        int lstar = __builtin_ctzll(bal);
        int cstar = 63 - lstar;
        uint32_t Pst = (uint32_t)__shfl((int)P, lstar, 64);
        uint32_t C1c = Pst - chs[cstar];
        uint32_t w = (lane < 32) ? lh[cstar * 32 + 31 - lane] : 0u;
        uint32_t Q = w;
        for (int d = 1; d < 32; d <<= 1) {
            uint32_t u = __shfl_up(Q, d, 64);
            if (lane >= d) Q += u;
        }
        uint64_t bal2 = __ballot((lane < 32) && (C1c + Q >= 1024u));
        int l2 = __builtin_ctzll(bal2);
        if (lane == 0) sB = cstar * 32 + 31 - l2;
    }
    __syncthreads();
    int B = sB;

    int src0 = g * 512;
#pragma unroll
    for (int k = 0; k < 2; ++k) {
        uint64_t key = pk[src0 + tid + k * 256];
        bool pred = (key != 0ull) && (val_bin(key_score(key)) >= B);
        uint64_t bal = __ballot(pred);
        int bs = 0;
        if (lane == 0 && bal) bs = atomicAdd(&sNP, (int)__popcll(bal));
        bs = __shfl(bs, 0, 64);
        if (pred) pass[bs + __popcll(bal & ((1ull << lane) - 1ull))] = key;
    }
    __syncthreads();
    int np = sNP;

    double lm = -1e300;
    if (tid < np) {
        uint64_t key = pass[tid];
        double s = key_score(key);
        int bin = val_bin(s);
        int c = bin >> 5;
        uint32_t rank = chsuf[c];
        for (int j = bin + 1; j < (c + 1) * 32; ++j) rank += lh[j];
        uint32_t bc = bcnt[b * 2048 + bin];
        if (bc <= BCAP) {
            const uint64_t* bk = bucket + ((size_t)b * 2048 + bin) * BCAP;
            for (uint32_t i = 0; i < bc; ++i) rank += (bk[i] > key) ? 1u : 0u;
        } else {
            for (int t2 = 0; t2 < PPAD; ++t2) {   // exact fallback (never taken)
                uint64_t k2 = pk[t2];
                if (k2 > key && val_bin(key_score(k2)) == bin) ++rank;
            }
        }

        if (rank < 1024u) {
            int idx = 0x3FFF - (int)(key & 0x3FFF);
            idx = idx < 0 ? 0 : (idx > P_TOTAL - 1 ? P_TOTAL - 1 : idx);

            int base2, w2, hw, st;
            const float* reg;
            if (idx < 10000)      { base2 = 0;     w2 = 100; hw = 10000; st = 8;   reg = r0; }
            else if (idx < 12500) { base2 = 10000; w2 = 50;  hw = 2500;  st = 16;  reg = r1; }
            else if (idx < 13125) { base2 = 12500; w2 = 25;  hw = 625;   st = 32;  reg = r2; }
            else if (idx < 13294) { base2 = 13125; w2 = 13;  hw = 169;   st = 64;  reg = r3; }
            else                  { base2 = 13294; w2 = 7;   hw = 49;    st = 128; reg = r4; }
            int yx = idx - base2;
            int y = yx / w2;
            int x = yx - y * w2;
            double sx = (double)(x * st + st / 2);
            double sy = (double)(y * st + st / 2);
            const float* rp = reg + (size_t)b * 4 * hw + yx;
            double x1 = sx - (double)rp[0];
            double y1 = sy - (double)rp[hw];
            double x2 = sx + (double)rp[2 * (size_t)hw];
            double y2 = sy + (double)rp[3 * (size_t)hw];
            int cv = classes[(size_t)b * P_TOTAL + idx];

            bool valid = (rank < KTOP) && (s >= D_SCORE_THR);
            size_t ix = (size_t)b * 1024 + rank;
            rawbox[ix] = make_double4(x1, y1, x2, y2);
            clsall[ix] = (float)cv;
            if (rank < KTOP) {
                outs[ix] = (float)s;
                outc[ix] = (float)cv;
                ((float4*)outb)[ix] = make_float4((float)x1, (float)y1,
                                                  (float)x2, (float)y2);
                lm = valid ? fmax(fmax(x1, y1), fmax(x2, y2)) : 0.0;
            }
            if (valid)
                atomicOr((unsigned long long*)&keepw[(size_t)b * 16 + (rank >> 6)],
                         1ull << (rank & 63));
        }
    }

    for (int d = 1; d < 64; d <<= 1)
        lm = fmax(lm, __shfl_xor(lm, d, 64));
    if (lane == 0) redw[wid] = lm;
    __syncthreads();
    if (tid == 0) {
        double mm = fmax(fmax(redw[0], redw[1]), fmax(redw[2], redw[3]));
        atomicMax(&pmaxE[b], enc64(mm));
    }
}

// ---------------- S2: mask matrix, 2 blocks per row-block (verified R17 body) ---

__global__ __launch_bounds__(256) void k_mask(
    const double4* __restrict__ rawbox, const float* __restrict__ clsall,
    const unsigned long long* __restrict__ pmaxE,
    uint64_t* __restrict__ M, uint64_t* __restrict__ D,
    uint32_t* __restrict__ Rnz)
{
    __shared__ double lx1[1024], ly1[1024], lx2[1024], ly2[1024], lar[1024];
    __shared__ float4 fbox[1024];
    int bid = blockIdx.x;
    int b = bid >> 5, rb = (bid >> 1) & 15, h = bid & 1;
    int tid = threadIdx.x;

    double offscale = dec64(pmaxE[b]) + 1.0;

    for (int t = tid; t < 1024; t += 256) {
        size_t ix = (size_t)b * 1024 + t;
        double4 rb4 = rawbox[ix];
        double o = (double)clsall[ix] * offscale;
        double ox1 = rb4.x + o, oy1 = rb4.y + o;
        double ox2 = rb4.z + o, oy2 = rb4.w + o;
        lx1[t] = ox1; ly1[t] = oy1; lx2[t] = ox2; ly2[t] = oy2;
        lar[t] = (ox2 - ox1 + 1.0) * (oy2 - oy1 + 1.0);
        fbox[t] = make_float4((float)ox1, (float)oy1, (float)ox2, (float)oy2);
    }
    __syncthreads();

    int ww = tid >> 6;
    int l  = tid & 63;
    int r  = rb * 64 + l;
    float4 fr = fbox[r];
    double rx1 = lx1[r], ry1 = ly1[r], rx2 = lx2[r], ry2 = ly2[r], ra = lar[r];
    int wbase = h * 8 + ww * 2;

    uint64_t bits0 = 0, bits1 = 0;

#define COLWORD(Q, BITS)                                                       \
    {                                                                          \
        int cb = (wbase + (Q)) * 64;                                           \
        if (cb + 63 > r) {                                                     \
            for (int kk = 0; kk < 64; ++kk) {                                  \
                int j = cb + kk;                                               \
                float4 fb = fbox[j];                                           \
                float xm = fminf(fb.z, fr.z) - fmaxf(fb.x, fr.x);              \
                float ym = fminf(fb.w, fr.w) - fmaxf(fb.y, fr.y);              \
                if (xm > -0.5f && ym > -0.5f) {                                \
                    double xmn = fmax(lx1[j], rx1);                            \
                    double ymn = fmax(ly1[j], ry1);                            \
                    double xmx = fmin(lx2[j], rx2);                            \
                    double ymx = fmin(ly2[j], ry2);                            \
                    double iw = xmx - xmn; iw = iw < 0.0 ? 0.0 : iw;           \
                    double ih = ymx - ymn; ih = ih < 0.0 ? 0.0 : ih;           \
                    double inter = iw * ih;                                    \
                    double iou = inter / (ra + lar[j] - inter);                \
                    BITS |= ((uint64_t)((j > r) && (iou > D_IOU_THR))) << kk;  \
                }                                                              \
            }                                                                  \
        }                                                                      \
    }

    COLWORD(0, bits0) COLWORD(1, bits1)
#undef COLWORD

    size_t mrow = ((size_t)b * 1024 + r) * 16 + wbase;
    M[mrow + 0] = bits0; M[mrow + 1] = bits1;

    if (h == (rb >> 3) && ww == ((rb & 7) >> 1)) {
        uint64_t db = ((rb & 1) == 0) ? bits0 : bits1;
        D[((size_t)b * 16 + rb) * 64 + l] = db;
    }

    uint64_t orw = bits0 | bits1;
    if (orw) atomicOr(&Rnz[(size_t)b * 1024 + r], 1u);
}

// ---------------- S3: one-wave sparse scan (verified body) ----------------

#define LOADC(G)                                                               \
    C0  = Mb[((size_t)(G) * 64 +  0 + p) * 16 + w];                            \
    C1  = Mb[((size_t)(G) * 64 +  4 + p) * 16 + w];                            \
    C2  = Mb[((size_t)(G) * 64 +  8 + p) * 16 + w];                            \
    C3  = Mb[((size_t)(G) * 64 + 12 + p) * 16 + w];                            \
    C4  = Mb[((size_t)(G) * 64 + 16 + p) * 16 + w];                            \
    C5  = Mb[((size_t)(G) * 64 + 20 + p) * 16 + w];                            \
    C6  = Mb[((size_t)(G) * 64 + 24 + p) * 16 + w];                            \
    C7  = Mb[((size_t)(G) * 64 + 28 + p) * 16 + w];                            \
    C8  = Mb[((size_t)(G) * 64 + 32 + p) * 16 + w];                            \
    C9  = Mb[((size_t)(G) * 64 + 36 + p) * 16 + w];                            \
    C10 = Mb[((size_t)(G) * 64 + 40 + p) * 16 + w];                            \
    C11 = Mb[((size_t)(G) * 64 + 44 + p) * 16 + w];                            \
    C12 = Mb[((size_t)(G) * 64 + 48 + p) * 16 + w];                            \
    C13 = Mb[((size_t)(G) * 64 + 52 + p) * 16 + w];                            \
    C14 = Mb[((size_t)(G) * 64 + 56 + p) * 16 + w];                            \
    C15 = Mb[((size_t)(G) * 64 + 60 + p) * 16 + w];

#define APPLY_Q(q)                                                             \
    {                                                                          \
        uint64_t t_ = (alive >> (4 * (q) + p)) & 1ull;                         \
        acc &= ~(C##q & (0ull - t_));                                          \
    }

#define STEPG(G)                                                               \
    {                                                                          \
        uint64_t kg = rl64(kw, (G));                                           \
        if (kg & nz##G) {                                                      \
            uint64_t dg = Dp[(size_t)(G) * 64 + lane];                         \
            LOADC(G)                                                           \
            uint64_t cur = kg, it = kg & nz##G;                                \
            while (it) {                                                       \
                int kk = __builtin_ctzll(it);                                  \
                uint64_t dk = rl64(dg, kk);                                    \
                cur &= ~dk;                                                    \
                it &= ~dk;                                                     \
                it &= it - 1ull;                                               \
            }                                                                  \
            uint64_t alive = cur;                                              \
            uint64_t acc = ~0ull;                                              \
            APPLY_Q(0)  APPLY_Q(1)  APPLY_Q(2)  APPLY_Q(3)                     \
            APPLY_Q(4)  APPLY_Q(5)  APPLY_Q(6)  APPLY_Q(7)                     \
            APPLY_Q(8)  APPLY_Q(9)  APPLY_Q(10) APPLY_Q(11)                    \
            APPLY_Q(12) APPLY_Q(13) APPLY_Q(14) APPLY_Q(15)                    \
            acc &= __shfl_xor(acc, 16, 64);                                    \
            acc &= __shfl_xor(acc, 32, 64);                                    \
            kw &= acc;                                                         \
        }                                                                      \
    }

__global__ __launch_bounds__(64, 1) void k_scan(
    const uint64_t* __restrict__ M, const uint64_t* __restrict__ D,
    const uint32_t* __restrict__ Rnz, const uint64_t* __restrict__ keepw,
    const float* __restrict__ outs, const float* __restrict__ outc,
    const float* __restrict__ outb, float* __restrict__ out)
{
    int b = blockIdx.x;
    int lane = threadIdx.x;          // one wave
    int p = (lane >> 4) & 3;         // replica 0..3
    int w = lane & 15;               // word index
    const uint64_t* Mb = M + (size_t)b * 1024 * 16;
    const uint64_t* Dp = D + (size_t)b * 1024;
    const uint32_t* Rp = Rnz + (size_t)b * 1024;

    uint64_t kw = keepw[(size_t)b * 16 + w];   // word w, replicated x4

    uint32_t f0  = Rp[0 * 64 + lane],  f1  = Rp[1 * 64 + lane];
    uint32_t f2  = Rp[2 * 64 + lane],  f3  = Rp[3 * 64 + lane];
    uint32_t f4  = Rp[4 * 64 + lane],  f5  = Rp[5 * 64 + lane];
    uint32_t f6  = Rp[6 * 64 + lane],  f7  = Rp[7 * 64 + lane];
    uint32_t f8  = Rp[8 * 64 + lane],  f9  = Rp[9 * 64 + lane];
    uint32_t f10 = Rp[10 * 64 + lane], f11 = Rp[11 * 64 + lane];
    uint32_t f12 = Rp[12 * 64 + lane], f13 = Rp[13 * 64 + lane];
    uint32_t f14 = Rp[14 * 64 + lane], f15 = Rp[15 * 64 + lane];
    uint64_t nz0  = __ballot(f0 != 0),  nz1  = __ballot(f1 != 0);
    uint64_t nz2  = __ballot(f2 != 0),  nz3  = __ballot(f3 != 0);
    uint64_t nz4  = __ballot(f4 != 0),  nz5  = __ballot(f5 != 0);
    uint64_t nz6  = __ballot(f6 != 0),  nz7  = __ballot(f7 != 0);
    uint64_t nz8  = __ballot(f8 != 0),  nz9  = __ballot(f9 != 0);
    uint64_t nz10 = __ballot(f10 != 0), nz11 = __ballot(f11 != 0);
    uint64_t nz12 = __ballot(f12 != 0), nz13 = __ballot(f13 != 0);
    uint64_t nz14 = __ballot(f14 != 0), nz15 = __ballot(f15 != 0);

    uint64_t C0,C1,C2,C3,C4,C5,C6,C7,C8,C9,C10,C11,C12,C13,C14,C15;

    STEPG(0)  STEPG(1)  STEPG(2)  STEPG(3)
    STEPG(4)  STEPG(5)  STEPG(6)  STEPG(7)
    STEPG(8)  STEPG(9)  STEPG(10) STEPG(11)
    STEPG(12) STEPG(13) STEPG(14) STEPG(15)

#pragma unroll
    for (int t = 0; t < 16; ++t) {
        int j = t * 64 + lane;
        uint64_t kwt = rl64(kw, t);
        bool kp = (kwt >> lane) & 1ull;
        if (j < KTOP) {
            size_t ix = (size_t)b * 1024 + j;
            out[(size_t)b * KTOP + j] = kp ? outs[ix] : 0.0f;
            out[(size_t)NB * KTOP + (size_t)b * KTOP + j] = kp ? outc[ix] : 0.0f;
            float4 bb = kp ? ((const float4*)outb)[ix] : make_float4(0.f, 0.f, 0.f, 0.f);
            ((float4*)(out + 2 * (size_t)NB * KTOP))[(size_t)b * KTOP + j] = bb;
        }
    }
}

// ---------------- launch ----------------

extern "C" void kernel_launch(void* const* d_in, const int* in_sizes, int n_in,
                              void* d_out, int out_size, void* d_ws, size_t ws_size,
                              hipStream_t stream) {
    const float* cls[5];
    const float* cnt[5];
    const float* reg[5];
    for (int i = 0; i < 5; ++i) {
        cls[i] = (const float*)d_in[i];
        cnt[i] = (const float*)d_in[5 + i];
        reg[i] = (const float*)d_in[10 + i];
    }
    float* out = (float*)d_out;

    // ws layout (bytes); M reuses the packed region (packed dead after k_rankprep)
    char* ws = (char*)d_ws;
    uint64_t* packed  = (uint64_t*)(ws + 0);          // 1,048,576
    uint64_t* M       = (uint64_t*)(ws + 0);          // 1,048,576 (reuse)
    int*      classes = (int*)     (ws + 1048576);    // 426,976 -> 1,475,552
    uint32_t* bcnt    = (uint32_t*)(ws + 1541088);    // 65,536  -> 1,606,624
    uint64_t* bucket  = (uint64_t*)(ws + 1606624);    // 33,554,432 -> 35,161,056
    double4*  rawbox  = (double4*) (ws + 35161056);   // 262,144 (32B aligned) -> 35,423,200
    float*    clsall  = (float*)   (ws + 35423200);   // 32,768 -> 35,455,968
    unsigned long long* pmaxE = (unsigned long long*)(ws + 35455968);  // 64 -> 35,456,032
    uint64_t* keepw   = (uint64_t*)(ws + 35456032);   // 1,024 -> 35,457,056
    uint64_t* D       = (uint64_t*)(ws + 35457056);   // 65,536 -> 35,522,592
    uint32_t* Rnz     = (uint32_t*)(ws + 35522592);   // 32,768 -> 35,555,360
    float*    outs    = (float*)   (ws + 35555360);   // 32,768 -> 35,588,128
    float*    outc    = (float*)   (ws + 35588128);   // 32,768 -> 35,620,896
    float*    outb    = (float*)   (ws + 35620896);   // 131,072 (16B aligned) -> 35,751,968

    k_zero<<<64, 256, 0, stream>>>(bcnt);

    k_scores<<<513, 256, 0, stream>>>(
        cls[0], cls[1], cls[2], cls[3], cls[4],
        cnt[0], cnt[1], cnt[2], cnt[3], cnt[4],
        packed, classes, bcnt, bucket, Rnz, keepw, pmaxE);

    k_rankprep<<<NB * 32, 256, 0, stream>>>(packed, bcnt, bucket, classes,
                                            reg[0], reg[1], reg[2], reg[3], reg[4],
                                            rawbox, clsall, outs, outc, outb,
                                            keepw, pmaxE);

    k_mask<<<NB * 32, 256, 0, stream>>>(rawbox, clsall, pmaxE, M, D, Rnz);

    k_scan<<<NB, 64, 0, stream>>>(M, D, Rnz, keepw, outs, outc, outb, out);
}